// Round 1
// baseline (1502.669 us; speedup 1.0000x reference)
//
#include <hip/hip_runtime.h>
#include <hip/hip_fp16.h>

#define DEVI __device__ __forceinline__

// B=4, C=128, H=W=256, Wf=129 (stored stride 132), nb=8, bs=16
#define WFP 132

DEVI float2 cmul(float2 a, float2 b){ return make_float2(fmaf(a.x,b.x,-(a.y*b.y)), fmaf(a.x,b.y,a.y*b.x)); }
DEVI float2 h2f2(__half2 v){ return make_float2(__low2float(v), __high2float(v)); }
DEVI __half2 f2h2(float a, float b){ return __floats2half2_rn(a, b); }
DEVI int rev4(int k){ return ((k&3)<<6) | (((k>>2)&3)<<4) | (((k>>4)&3)<<2) | ((k>>6)&3); }
DEVI float gelu(float v){ return 0.5f*v*(1.0f + erff(v*0.70710678118654752f)); }
DEVI float sshrink(float v){ return v > 0.01f ? v-0.01f : (v < -0.01f ? v+0.01f : 0.0f); }

// In-place FFT over `rows` rows of 256 complex values (half2 in LDS, fp32 math).
// DIR=-1: forward DIF (natural in -> base-4 digit-reversed out).
// DIR=+1: inverse DIT (digit-reversed in -> natural out, UNNORMALIZED).
template<int DIR>
DEVI void fft256(__half2* d, int rows, int tid, int nthr){
  const int nbf = rows<<6;
  #pragma unroll
  for (int si=0; si<4; ++si){
    const int lq = (DIR<0) ? (6-2*si) : (2*si);
    const int q4 = 1<<lq;
    const int tws = 64>>lq;
    for (int u = tid; u < nbf; u += nthr){
      const int row = u>>6, w = u&63;
      const int j = w & (q4-1);
      const int blk = w >> lq;
      const int base = (row<<8) + (blk<<(lq+2)) + j;
      const int e = j*tws;                       // twiddle exponent (units of 2pi/256), e<192
      float sn, cs;
      sincosf((float)(DIR*e) * 0.0245436926061703f, &sn, &cs);  // DIR<0 -> e^{-i t}
      const float2 w1 = make_float2(cs, sn);
      const float2 w2 = make_float2(cs*cs - sn*sn, 2.f*cs*sn);
      const float2 w3 = cmul(w2, w1);
      if (DIR < 0){
        float2 x0 = h2f2(d[base]);
        float2 x1 = h2f2(d[base+q4]);
        float2 x2 = h2f2(d[base+2*q4]);
        float2 x3 = h2f2(d[base+3*q4]);
        float2 t0 = make_float2(x0.x+x2.x, x0.y+x2.y);
        float2 t1 = make_float2(x0.x-x2.x, x0.y-x2.y);
        float2 t2 = make_float2(x1.x+x3.x, x1.y+x3.y);
        float2 t3 = make_float2(x1.y-x3.y, x3.x-x1.x);     // -i*(x1-x3)
        float2 u1 = cmul(make_float2(t1.x+t3.x, t1.y+t3.y), w1);
        float2 u2 = cmul(make_float2(t0.x-t2.x, t0.y-t2.y), w2);
        float2 u3 = cmul(make_float2(t1.x-t3.x, t1.y-t3.y), w3);
        d[base]      = f2h2(t0.x+t2.x, t0.y+t2.y);
        d[base+q4]   = f2h2(u1.x, u1.y);
        d[base+2*q4] = f2h2(u2.x, u2.y);
        d[base+3*q4] = f2h2(u3.x, u3.y);
      } else {
        float2 x0  = h2f2(d[base]);
        float2 b1v = cmul(h2f2(d[base+q4]),   w1);
        float2 b2v = cmul(h2f2(d[base+2*q4]), w2);
        float2 b3v = cmul(h2f2(d[base+3*q4]), w3);
        float2 t0 = make_float2(x0.x+b2v.x, x0.y+b2v.y);
        float2 t1 = make_float2(x0.x-b2v.x, x0.y-b2v.y);
        float2 t2 = make_float2(b1v.x+b3v.x, b1v.y+b3v.y);
        float2 t3 = make_float2(-(b1v.y-b3v.y), b1v.x-b3v.x); // +i*(b1-b3)
        d[base]      = f2h2(t0.x+t2.x, t0.y+t2.y);
        d[base+q4]   = f2h2(t1.x+t3.x, t1.y+t3.y);
        d[base+2*q4] = f2h2(t0.x-t2.x, t0.y-t2.y);
        d[base+3*q4] = f2h2(t1.x-t3.x, t1.y-t3.y);
      }
    }
    __syncthreads();
  }
}

// ---------------- K1: GEMM1 + GELU + rfft along W ----------------
// grid 1024 = (b<<8)|h, block 256 (thread = pixel w)
__global__ __launch_bounds__(256, 2) void k_front(
    const float* __restrict__ xg, const float* __restrict__ p1w,
    const float* __restrict__ p1b, __half2* __restrict__ buf1)
{
  __shared__ __half2 fb[64*256];   // 64 packed complex rows (channel pairs)
  const int t = threadIdx.x;
  const int b = blockIdx.x >> 8, h = blockIdx.x & 255;

  // x column x[b][ci][h][t] into registers (coalesced per ci)
  const float* xp = xg + (size_t)b*8388608 + (size_t)h*256 + t;
  float xv[128];
  #pragma unroll
  for (int ci=0; ci<128; ++ci) xv[ci] = xp[(size_t)ci*65536];

  // GEMM1 (VALU fp32, weights via uniform scalar loads) + GELU, pack pairs
  for (int co=0; co<128; co+=2){
    const float* w0 = p1w + (co<<7);
    const float* w1 = w0 + 128;
    float a0 = p1b[co], a1 = p1b[co+1];
    #pragma unroll
    for (int ci=0; ci<128; ++ci){ const float xc = xv[ci]; a0 = fmaf(xc, w0[ci], a0); a1 = fmaf(xc, w1[ci], a1); }
    fb[((co>>1)<<8) + t] = f2h2(gelu(a0), gelu(a1));
  }
  __syncthreads();

  fft256<-1>(fb, 64, t, 256);

  // hermitian unpack of packed real pair, ortho scale 1/16 (0.03125 includes the 1/2)
  for (int it=0; it<32; ++it){
    const int idx = (it<<8) + t;
    const int r = idx>>7, k = idx&127;
    const float2 zk = h2f2(fb[(r<<8) + rev4(k)]);
    const float2 zm = h2f2(fb[(r<<8) + rev4((256-k)&255)]);
    const float ar = (zk.x+zm.x)*0.03125f, ai = (zk.y-zm.y)*0.03125f;
    const float br = (zk.y+zm.y)*0.03125f, bi = (zm.x-zk.x)*0.03125f;
    const size_t pa = ((size_t)(b*128 + 2*r)*256 + h)*WFP + k;
    buf1[pa]           = f2h2(ar, ai);
    buf1[pa + 256*WFP] = f2h2(br, bi);
  }
  if (t < 64){   // k = 128 (Nyquist)
    const int r = t;
    const float2 zk = h2f2(fb[(r<<8) + rev4(128)]);
    const size_t pa = ((size_t)(b*128 + 2*r)*256 + h)*WFP + 128;
    buf1[pa]           = f2h2(zk.x*0.0625f, 0.f);
    buf1[pa + 256*WFP] = f2h2(zk.y*0.0625f, 0.f);
  }
}

// ---------------- T1: [B][C][H][132] -> [B][n][wf][i][H] ----------------
// grid (5, 1024, 4): x=wf-tile, y=(c<<3)|h-tile, z=b
__global__ __launch_bounds__(256) void k_t1(const __half2* __restrict__ src, __half2* __restrict__ dst)
{
  __shared__ __half2 tile[32][33];
  const int t = threadIdx.x;
  const int wt = blockIdx.x;
  const int ht = blockIdx.y & 7, c = blockIdx.y >> 3, b = blockIdx.z;
  const int h0 = ht<<5, wf0 = wt<<5;
  const int tr = t>>5, tc = t&31;
  const size_t sbase = (size_t)(b*128 + c)*256;
  #pragma unroll
  for (int p=0; p<4; ++p){
    const int hh = h0 + (p<<3) + tr, wf = wf0 + tc;
    if (wf < 129) tile[(p<<3)+tr][tc] = src[(sbase + hh)*WFP + wf];
  }
  __syncthreads();
  const int n = c>>4, ii = c&15;
  const size_t dbase = (size_t)(b*8 + n)*129;
  #pragma unroll
  for (int p=0; p<4; ++p){
    const int wf = wf0 + (p<<3) + tr, hh = h0 + tc;
    if (wf < 129) dst[((dbase + wf)*16 + ii)*256 + hh] = tile[tc][(p<<3)+tr];
  }
}

// ---------------- K3: FFT along H + complex block-MLP + inverse ----------------
// grid (129, 8, 4): x=wf, y=n, z=b; block 256 (thread = kh point, digit-reversed order)
__global__ __launch_bounds__(256) void k_spec(__half2* __restrict__ buf2,
    const float* __restrict__ w1, const float* __restrict__ b1,
    const float* __restrict__ w2, const float* __restrict__ b2)
{
  __shared__ __half2 data[16*256];
  const int t = threadIdx.x;
  const int wf = blockIdx.x, n = blockIdx.y, b = blockIdx.z;
  __half2* chunk = buf2 + ((size_t)((b*8 + n)*129 + wf) << 12);
  #pragma unroll
  for (int p=0; p<4; ++p) ((float4*)data)[(p<<8)+t] = ((const float4*)chunk)[(p<<8)+t];
  __syncthreads();

  fft256<-1>(data, 16, t, 256);

  // MLP at this thread's frequency point (column-private in LDS: no barrier needed)
  float xr[16], xi[16], or_[16], oi_[16];
  #pragma unroll
  for (int i=0;i<16;++i){ const float2 z = h2f2(data[(i<<8)+t]); xr[i]=z.x*0.0625f; xi[i]=z.y*0.0625f; }
  const float* w1r = w1 + (n<<8);
  const float* w1i = w1 + 2048 + (n<<8);
  const float* b1r = b1 + (n<<4);
  const float* b1i = b1 + 128 + (n<<4);
  #pragma unroll
  for (int o=0;o<16;++o){ or_[o]=b1r[o]; oi_[o]=b1i[o]; }
  #pragma unroll
  for (int i=0;i<16;++i){
    const float ar=xr[i], ai=xi[i];
    #pragma unroll
    for (int o=0;o<16;++o){
      const float wr = w1r[(i<<4)+o], wi = w1i[(i<<4)+o];
      or_[o] = fmaf(ar,wr,fmaf(-ai,wi,or_[o]));
      oi_[o] = fmaf(ai,wr,fmaf( ar,wi,oi_[o]));
    }
  }
  #pragma unroll
  for (int o=0;o<16;++o){ or_[o] = fmaxf(or_[o],0.f); oi_[o] = fmaxf(oi_[o],0.f); }
  const float* w2r = w2 + (n<<8);
  const float* w2i = w2 + 2048 + (n<<8);
  const float* b2r = b2 + (n<<4);
  const float* b2i = b2 + 128 + (n<<4);
  #pragma unroll
  for (int o=0;o<16;++o){ xr[o]=b2r[o]; xi[o]=b2i[o]; }
  #pragma unroll
  for (int i=0;i<16;++i){
    const float ar=or_[i], ai=oi_[i];
    #pragma unroll
    for (int o=0;o<16;++o){
      const float wr = w2r[(i<<4)+o], wi = w2i[(i<<4)+o];
      xr[o] = fmaf(ar,wr,fmaf(-ai,wi,xr[o]));
      xi[o] = fmaf(ai,wr,fmaf( ar,wi,xi[o]));
    }
  }
  #pragma unroll
  for (int o=0;o<16;++o) data[(o<<8)+t] = f2h2(sshrink(xr[o]), sshrink(xi[o]));
  __syncthreads();

  fft256<1>(data, 16, t, 256);   // unnormalized inverse (16x ortho)

  #pragma unroll
  for (int p=0; p<4; ++p) ((float4*)chunk)[(p<<8)+t] = ((const float4*)data)[(p<<8)+t];
}

// ---------------- T2: [B][n][wf][i][H] -> [B][C][H][132] ----------------
__global__ __launch_bounds__(256) void k_t2(const __half2* __restrict__ src, __half2* __restrict__ dst)
{
  __shared__ __half2 tile[32][33];
  const int t = threadIdx.x;
  const int wt = blockIdx.x;
  const int ht = blockIdx.y & 7, c = blockIdx.y >> 3, b = blockIdx.z;
  const int h0 = ht<<5, wf0 = wt<<5;
  const int tr = t>>5, tc = t&31;
  const int n = c>>4, ii = c&15;
  const size_t sbase = (size_t)(b*8 + n)*129;
  #pragma unroll
  for (int p=0; p<4; ++p){
    const int wf = wf0 + (p<<3) + tr, hh = h0 + tc;
    if (wf < 129) tile[(p<<3)+tr][tc] = src[((sbase + wf)*16 + ii)*256 + hh];  // tile[wfrel][hrel]
  }
  __syncthreads();
  const size_t dbase = (size_t)(b*128 + c)*256;
  #pragma unroll
  for (int p=0; p<4; ++p){
    const int hh = h0 + (p<<3) + tr, wf = wf0 + tc;
    if (wf < 129) dst[(dbase + hh)*WFP + wf] = tile[tc][(p<<3)+tr];
  }
}

// ---------------- K5: irfft along W + AFNO residual + GEMM2 + shortcut ----------------
// grid 1024 = (b<<8)|h, block 256 (thread = pixel w)
__global__ __launch_bounds__(256, 2) void k_back(
    const __half2* __restrict__ buf1, const float* __restrict__ xg,
    const float* __restrict__ p1w, const float* __restrict__ p1b,
    const float* __restrict__ p2w, const float* __restrict__ p2b,
    float* __restrict__ outg)
{
  __shared__ __half2 fb[64*256];
  const int t = threadIdx.x;
  const int b = blockIdx.x >> 8, h = blockIdx.x & 255;

  // build hermitian-extended packed spectra Z = A + iB, store digit-reversed
  const int k = t;
  const int km = (256 - t) & 255;
  const bool lo = (k <= 128);
  const int kk = lo ? k : km;
  for (int it=0; it<64; ++it){
    const size_t pa = ((size_t)(b*128 + 2*it)*256 + h)*WFP;
    const float2 va = h2f2(buf1[pa + kk]);
    const float2 vb = h2f2(buf1[pa + 256*WFP + kk]);
    float2 Z = lo ? make_float2(va.x - vb.y, va.y + vb.x)
                  : make_float2(va.x + vb.y, vb.x - va.y);
    if (k == 0 || k == 128) Z = make_float2(va.x, vb.x);  // c2r: drop imag at DC/Nyquist
    fb[(it<<8) + rev4(k)] = f2h2(Z.x, Z.y);
  }
  __syncthreads();

  fft256<1>(fb, 64, t, 256);   // y (unnormalized: 256x ortho) now spatial in fb

  // phase A: s = gelu(p1*x + p1b) + y/256, stored in place in fb (column-private)
  const float* xp = xg + (size_t)b*8388608 + (size_t)h*256 + t;
  float xv[128];
  #pragma unroll
  for (int ci=0; ci<128; ++ci) xv[ci] = xp[(size_t)ci*65536];
  for (int c=0; c<128; c+=2){
    const float* w0 = p1w + (c<<7);
    const float* w1 = w0 + 128;
    float a0 = p1b[c], a1 = p1b[c+1];
    #pragma unroll
    for (int ci=0; ci<128; ++ci){ const float xc = xv[ci]; a0 = fmaf(xc, w0[ci], a0); a1 = fmaf(xc, w1[ci], a1); }
    const float2 y2 = h2f2(fb[((c>>1)<<8) + t]);
    fb[((c>>1)<<8) + t] = f2h2(gelu(a0) + y2.x*0.00390625f, gelu(a1) + y2.y*0.00390625f);
  }

  // phase B: out = p2*s + p2b + x
  float sv[128];
  #pragma unroll
  for (int r=0; r<64; ++r){ const float2 s2 = h2f2(fb[(r<<8)+t]); sv[2*r]=s2.x; sv[2*r+1]=s2.y; }
  for (int o=0; o<128; ++o){
    const float* wr = p2w + (o<<7);
    float a = p2b[o];
    #pragma unroll
    for (int c=0; c<128; ++c) a = fmaf(sv[c], wr[c], a);
    const size_t oi = ((size_t)(b*128 + o)*256 + h)*256 + t;
    outg[oi] = a + xg[oi];
  }
}

extern "C" void kernel_launch(void* const* d_in, const int* in_sizes, int n_in,
                              void* d_out, int out_size, void* d_ws, size_t ws_size,
                              hipStream_t stream)
{
  (void)in_sizes; (void)n_in; (void)out_size; (void)ws_size;
  const float* x   = (const float*)d_in[0];
  const float* p1w = (const float*)d_in[1];
  const float* p1b = (const float*)d_in[2];
  const float* w1  = (const float*)d_in[3];
  const float* b1  = (const float*)d_in[4];
  const float* w2  = (const float*)d_in[5];
  const float* b2  = (const float*)d_in[6];
  const float* p2w = (const float*)d_in[7];
  const float* p2b = (const float*)d_in[8];
  float* out = (float*)d_out;

  // buf1: [B][C][H][WFP] half2  = 69.2 MB  (workspace)
  // buf2: [B][8][129][16][H] half2 = 67.6 MB, placed in d_out (fully consumed by
  // k_t2 before k_back rewrites every element of d_out).
  __half2* buf1 = (__half2*)d_ws;
  __half2* buf2 = (__half2*)d_out;

  k_front<<<dim3(1024), dim3(256), 0, stream>>>(x, p1w, p1b, buf1);
  k_t1   <<<dim3(5, 1024, 4), dim3(256), 0, stream>>>(buf1, buf2);
  k_spec <<<dim3(129, 8, 4), dim3(256), 0, stream>>>(buf2, w1, b1, w2, b2);
  k_t2   <<<dim3(5, 1024, 4), dim3(256), 0, stream>>>(buf2, buf1);
  k_back <<<dim3(1024), dim3(256), 0, stream>>>(buf1, x, p1w, p1b, p2w, p2b, out);
}

// Round 3
// 513.634 us; speedup vs baseline: 2.9256x; 2.9256x over previous
//
#include <hip/hip_runtime.h>
#include <hip/hip_fp16.h>

#define DEVI __device__ __forceinline__

// B=4, C=128, H=W=256, Wf=129 (buf1 stride 132), nb=8, bs=16
#define WFP 132

typedef _Float16 f16;
typedef _Float16 f16x8 __attribute__((ext_vector_type(8)));
typedef _Float16 f16x2 __attribute__((ext_vector_type(2)));
typedef float    f32x16 __attribute__((ext_vector_type(16)));

DEVI float2 cmul(float2 a, float2 b){ return make_float2(fmaf(a.x,b.x,-(a.y*b.y)), fmaf(a.x,b.y,a.y*b.x)); }
DEVI float2 h2f2(__half2 v){ return make_float2(__low2float(v), __high2float(v)); }
DEVI __half2 f2h2(float a, float b){ return __floats2half2_rn(a, b); }
DEVI int rev4(int k){ return ((k&3)<<6) | (((k>>2)&3)<<4) | (((k>>4)&3)<<2) | ((k>>6)&3); }
DEVI float gelu(float v){ return 0.5f*v*(1.0f + erff(v*0.70710678118654752f)); }
DEVI float sshrink(float v){ return v > 0.01f ? v-0.01f : (v < -0.01f ? v+0.01f : 0.0f); }
DEVI f32x16 zero16(){
  f32x16 z;
#pragma unroll
  for (int i=0;i<16;++i) z[i]=0.f;
  return z;
}

// In-place FFT over `rows` rows of 256 complex values (half2 in LDS, fp32 math).
// DIR=-1: forward DIF (natural in -> base-4 digit-reversed out).
// DIR=+1: inverse DIT (digit-reversed in -> natural out, UNNORMALIZED).
template<int DIR>
DEVI void fft256(__half2* d, int rows, int tid, int nthr){
  const int nbf = rows<<6;
  #pragma unroll
  for (int si=0; si<4; ++si){
    const int lq = (DIR<0) ? (6-2*si) : (2*si);
    const int q4 = 1<<lq;
    const int tws = 64>>lq;
    for (int u = tid; u < nbf; u += nthr){
      const int row = u>>6, w = u&63;
      const int j = w & (q4-1);
      const int blk = w >> lq;
      const int base = (row<<8) + (blk<<(lq+2)) + j;
      const int e = j*tws;
      float sn, cs;
      __sincosf((float)(DIR*e) * 0.0245436926061703f, &sn, &cs);
      const float2 w1 = make_float2(cs, sn);
      const float2 w2 = make_float2(cs*cs - sn*sn, 2.f*cs*sn);
      const float2 w3 = cmul(w2, w1);
      if (DIR < 0){
        float2 x0 = h2f2(d[base]);
        float2 x1 = h2f2(d[base+q4]);
        float2 x2 = h2f2(d[base+2*q4]);
        float2 x3 = h2f2(d[base+3*q4]);
        float2 t0 = make_float2(x0.x+x2.x, x0.y+x2.y);
        float2 t1 = make_float2(x0.x-x2.x, x0.y-x2.y);
        float2 t2 = make_float2(x1.x+x3.x, x1.y+x3.y);
        float2 t3 = make_float2(x1.y-x3.y, x3.x-x1.x);
        float2 u1 = cmul(make_float2(t1.x+t3.x, t1.y+t3.y), w1);
        float2 u2 = cmul(make_float2(t0.x-t2.x, t0.y-t2.y), w2);
        float2 u3 = cmul(make_float2(t1.x-t3.x, t1.y-t3.y), w3);
        d[base]      = f2h2(t0.x+t2.x, t0.y+t2.y);
        d[base+q4]   = f2h2(u1.x, u1.y);
        d[base+2*q4] = f2h2(u2.x, u2.y);
        d[base+3*q4] = f2h2(u3.x, u3.y);
      } else {
        float2 x0  = h2f2(d[base]);
        float2 b1v = cmul(h2f2(d[base+q4]),   w1);
        float2 b2v = cmul(h2f2(d[base+2*q4]), w2);
        float2 b3v = cmul(h2f2(d[base+3*q4]), w3);
        float2 t0 = make_float2(x0.x+b2v.x, x0.y+b2v.y);
        float2 t1 = make_float2(x0.x-b2v.x, x0.y-b2v.y);
        float2 t2 = make_float2(b1v.x+b3v.x, b1v.y+b3v.y);
        float2 t3 = make_float2(-(b1v.y-b3v.y), b1v.x-b3v.x);
        d[base]      = f2h2(t0.x+t2.x, t0.y+t2.y);
        d[base+q4]   = f2h2(t1.x+t3.x, t1.y+t3.y);
        d[base+2*q4] = f2h2(t0.x-t2.x, t0.y-t2.y);
        d[base+3*q4] = f2h2(t1.x-t3.x, t1.y-t3.y);
      }
    }
    __syncthreads();
  }
}

// ---------------- TX: x [b][c][hw] fp32 -> xt [pg][c] f16 ----------------
// grid 4096: block = 64 pixels x 128 channels
__global__ __launch_bounds__(256) void k_tx(const float* __restrict__ xg, f16* __restrict__ xt)
{
  __shared__ f16 lt[64][136];   // [w][c], rows 272B (16B aligned)
  const int t = threadIdx.x;
  const size_t pg0 = (size_t)blockIdx.x * 64;
  const int b = (int)(pg0>>16), hw0 = (int)(pg0 & 65535);
  const int c0 = t>>4, w4 = (t&15)*4;
  #pragma unroll
  for (int i=0;i<8;++i){
    const int c = c0 + i*16;
    const float4 v = *(const float4*)(xg + ((size_t)(b*128+c)<<16) + hw0 + w4);
    lt[w4+0][c] = (f16)v.x; lt[w4+1][c] = (f16)v.y;
    lt[w4+2][c] = (f16)v.z; lt[w4+3][c] = (f16)v.w;
  }
  __syncthreads();
  const int w = t>>2, sb = (t&3)*32;
  #pragma unroll
  for (int i=0;i<4;++i)
    *(f16x8*)(xt + (pg0 + w)*128 + sb + 8*i) = *(const f16x8*)&lt[w][sb + 8*i];
}

// ---------------- GEMM1: h^T[pg][co] = gelu(p1w . x + p1b), f16, MFMA ----------------
// grid 2048: tile M=128 pixels x N=128 co, K=128 in 2 halves. 4 waves.
__global__ __launch_bounds__(256) void k_gemm1(const f16* __restrict__ xt, const float* __restrict__ w,
    const float* __restrict__ bias, f16* __restrict__ h2t)
{
  __shared__ f16 xa[128][72];
  __shared__ f16 wl[128][72];
  const int t = threadIdx.x, l = t&63, wid = t>>6;
  const int col = l&31;
  const size_t pg0 = (size_t)blockIdx.x * 128;
  f32x16 acc0=zero16(), acc1=zero16(), acc2=zero16(), acc3=zero16();
  for (int kk=0; kk<2; ++kk){
    __syncthreads();
    { const int row=t>>1, cb=(t&1)*32;
      const f16x8* src=(const f16x8*)(xt + (pg0+row)*128 + kk*64 + cb);
      f16x8* dst=(f16x8*)&xa[row][cb];
      dst[0]=src[0]; dst[1]=src[1]; dst[2]=src[2]; dst[3]=src[3]; }
    { const int row=t>>1, cb=(t&1)*32;
      const float4* src=(const float4*)(w + row*128 + kk*64 + cb);
      #pragma unroll
      for(int i=0;i<8;++i){ const float4 v=src[i];
        f16x2 p0={(f16)v.x,(f16)v.y}, p1={(f16)v.z,(f16)v.w};
        *(f16x2*)&wl[row][cb+4*i]=p0; *(f16x2*)&wl[row][cb+4*i+2]=p1; } }
    __syncthreads();
    #pragma unroll
    for (int c=0;c<4;++c){
      const int ko = c*16 + (l>>5)*8;
      const f16x8 a  = *(const f16x8*)&xa[wid*32+col][ko];
      const f16x8 b0 = *(const f16x8*)&wl[  0+col][ko];
      const f16x8 b1 = *(const f16x8*)&wl[ 32+col][ko];
      const f16x8 b2 = *(const f16x8*)&wl[ 64+col][ko];
      const f16x8 b3 = *(const f16x8*)&wl[ 96+col][ko];
      acc0 = __builtin_amdgcn_mfma_f32_32x32x16_f16(a, b0, acc0, 0,0,0);
      acc1 = __builtin_amdgcn_mfma_f32_32x32x16_f16(a, b1, acc1, 0,0,0);
      acc2 = __builtin_amdgcn_mfma_f32_32x32x16_f16(a, b2, acc2, 0,0,0);
      acc3 = __builtin_amdgcn_mfma_f32_32x32x16_f16(a, b3, acc3, 0,0,0);
    }
  }
  const int prow = wid*32 + 4*(l>>5);
  auto store1 = [&](const f32x16& A, int nt){
    const float bi = bias[nt*32+col];
    #pragma unroll
    for (int r=0;r<16;++r){
      const int p = prow + (r&3) + 8*(r>>2);
      const float v = A[r] + bi;
      h2t[(pg0+(size_t)p)*128 + nt*32+col] = (f16)gelu(v);
    }
  };
  store1(acc0,0); store1(acc1,1); store1(acc2,2); store1(acc3,3);
}

// ---------------- FFTW: rfft along W of h rows -> buf1 ----------------
// grid 1024 = (b<<8)|h, block 256 (thread = pixel w)
__global__ __launch_bounds__(256, 2) void k_fftw(const f16* __restrict__ h2t, __half2* __restrict__ buf1)
{
  __shared__ __half2 fb[64*256];
  const int t = threadIdx.x;
  const int b = blockIdx.x >> 8, h = blockIdx.x & 255;
  const size_t pg = (size_t)blockIdx.x*256 + t;
  const f16* row = h2t + pg*128;
  #pragma unroll
  for (int i=0;i<16;++i){
    const f16x8 v = ((const f16x8*)row)[i];
    const __half2* vp = (const __half2*)&v;
    #pragma unroll
    for (int j=0;j<4;++j) fb[(i*4+j)*256 + t] = vp[j];
  }
  __syncthreads();

  fft256<-1>(fb, 64, t, 256);

  for (int it=0; it<32; ++it){
    const int idx = (it<<8) + t;
    const int r = idx>>7, k = idx&127;
    const float2 zk = h2f2(fb[(r<<8) + rev4(k)]);
    const float2 zm = h2f2(fb[(r<<8) + rev4((256-k)&255)]);
    const float ar = (zk.x+zm.x)*0.03125f, ai = (zk.y-zm.y)*0.03125f;
    const float br = (zk.y+zm.y)*0.03125f, bi = (zm.x-zk.x)*0.03125f;
    const size_t pa = ((size_t)(b*128 + 2*r)*256 + h)*WFP + k;
    buf1[pa]           = f2h2(ar, ai);
    buf1[pa + 256*WFP] = f2h2(br, bi);
  }
  if (t < 64){
    const int r = t;
    const float2 zk = h2f2(fb[(r<<8) + rev4(128)]);
    const size_t pa = ((size_t)(b*128 + 2*r)*256 + h)*WFP + 128;
    buf1[pa]           = f2h2(zk.x*0.0625f, 0.f);
    buf1[pa + 256*WFP] = f2h2(zk.y*0.0625f, 0.f);
  }
}

// ---------------- T1: [B][C][H][132] cols 0..127 -> [B][n][wf][i][H] ----------------
// grid (4, 1024, 4)
__global__ __launch_bounds__(256) void k_t1(const __half2* __restrict__ src, __half2* __restrict__ dst)
{
  __shared__ __half2 tile[32][33];
  const int t = threadIdx.x;
  const int wt = blockIdx.x;
  const int ht = blockIdx.y & 7, c = blockIdx.y >> 3, b = blockIdx.z;
  const int h0 = ht<<5, wf0 = wt<<5;
  const int tr = t>>5, tc = t&31;
  const size_t sbase = (size_t)(b*128 + c)*256;
  #pragma unroll
  for (int p=0; p<4; ++p){
    const int hh = h0 + (p<<3) + tr, wf = wf0 + tc;
    tile[(p<<3)+tr][tc] = src[(sbase + hh)*WFP + wf];
  }
  __syncthreads();
  const int n = c>>4, ii = c&15;
  const size_t dbase = (size_t)(b*8 + n)*128;
  #pragma unroll
  for (int p=0; p<4; ++p){
    const int wf = wf0 + (p<<3) + tr, hh = h0 + tc;
    dst[((dbase + wf)*16 + ii)*256 + hh] = tile[tc][(p<<3)+tr];
  }
}

// ---------------- spec body: FFT along H + complex block-MLP + inverse ----------------
DEVI void spec_body(__half2* data, int n, const float* __restrict__ w1, const float* __restrict__ b1,
                    const float* __restrict__ w2, const float* __restrict__ b2, int t)
{
  fft256<-1>(data, 16, t, 256);
  float xr[16], xi[16], or_[16], oi_[16];
  #pragma unroll
  for (int i=0;i<16;++i){ const float2 z = h2f2(data[(i<<8)+t]); xr[i]=z.x*0.0625f; xi[i]=z.y*0.0625f; }
  const float* w1r = w1 + (n<<8);
  const float* w1i = w1 + 2048 + (n<<8);
  const float* b1r = b1 + (n<<4);
  const float* b1i = b1 + 128 + (n<<4);
  #pragma unroll
  for (int o=0;o<16;++o){ or_[o]=b1r[o]; oi_[o]=b1i[o]; }
  #pragma unroll
  for (int i=0;i<16;++i){
    const float ar=xr[i], ai=xi[i];
    #pragma unroll
    for (int o=0;o<16;++o){
      const float wr = w1r[(i<<4)+o], wi = w1i[(i<<4)+o];
      or_[o] = fmaf(ar,wr,fmaf(-ai,wi,or_[o]));
      oi_[o] = fmaf(ai,wr,fmaf( ar,wi,oi_[o]));
    }
  }
  #pragma unroll
  for (int o=0;o<16;++o){ or_[o] = fmaxf(or_[o],0.f); oi_[o] = fmaxf(oi_[o],0.f); }
  const float* w2r = w2 + (n<<8);
  const float* w2i = w2 + 2048 + (n<<8);
  const float* b2r = b2 + (n<<4);
  const float* b2i = b2 + 128 + (n<<4);
  #pragma unroll
  for (int o=0;o<16;++o){ xr[o]=b2r[o]; xi[o]=b2i[o]; }
  #pragma unroll
  for (int i=0;i<16;++i){
    const float ar=or_[i], ai=oi_[i];
    #pragma unroll
    for (int o=0;o<16;++o){
      const float wr = w2r[(i<<4)+o], wi = w2i[(i<<4)+o];
      xr[o] = fmaf(ar,wr,fmaf(-ai,wi,xr[o]));
      xi[o] = fmaf(ai,wr,fmaf( ar,wi,xi[o]));
    }
  }
  #pragma unroll
  for (int o=0;o<16;++o) data[(o<<8)+t] = f2h2(sshrink(xr[o]), sshrink(xi[o]));
  __syncthreads();
  fft256<1>(data, 16, t, 256);
}

// grid (128, 8, 4): wf<128 from buf2
__global__ __launch_bounds__(256) void k_spec(__half2* __restrict__ buf2,
    const float* __restrict__ w1, const float* __restrict__ b1,
    const float* __restrict__ w2, const float* __restrict__ b2)
{
  __shared__ __half2 data[16*256];
  const int t = threadIdx.x;
  const int wf = blockIdx.x, n = blockIdx.y, b = blockIdx.z;
  __half2* chunk = buf2 + ((size_t)((b*8 + n)*128 + wf) << 12);
  #pragma unroll
  for (int p=0; p<4; ++p) ((float4*)data)[(p<<8)+t] = ((const float4*)chunk)[(p<<8)+t];
  __syncthreads();
  spec_body(data, n, w1,b1,w2,b2, t);
  #pragma unroll
  for (int p=0; p<4; ++p) ((float4*)chunk)[(p<<8)+t] = ((const float4*)data)[(p<<8)+t];
}

// grid (8, 4): wf==128 (Nyquist) gathered straight from buf1 col 128
__global__ __launch_bounds__(256) void k_spec_nyq(__half2* __restrict__ buf1,
    const float* __restrict__ w1, const float* __restrict__ b1,
    const float* __restrict__ w2, const float* __restrict__ b2)
{
  __shared__ __half2 data[16*256];
  const int t = threadIdx.x;
  const int n = blockIdx.x, b = blockIdx.y;
  #pragma unroll
  for (int i=0;i<16;++i)
    data[(i<<8) + t] = buf1[((size_t)(b*128 + n*16 + i)*256 + t)*WFP + 128];
  __syncthreads();
  spec_body(data, n, w1,b1,w2,b2, t);
  #pragma unroll
  for (int i=0;i<16;++i)
    buf1[((size_t)(b*128 + n*16 + i)*256 + t)*WFP + 128] = data[(i<<8) + t];
}

// ---------------- T2: [B][n][wf][i][H] -> [B][C][H][132] cols 0..127 ----------------
__global__ __launch_bounds__(256) void k_t2(const __half2* __restrict__ src, __half2* __restrict__ dst)
{
  __shared__ __half2 tile[32][33];
  const int t = threadIdx.x;
  const int wt = blockIdx.x;
  const int ht = blockIdx.y & 7, c = blockIdx.y >> 3, b = blockIdx.z;
  const int h0 = ht<<5, wf0 = wt<<5;
  const int tr = t>>5, tc = t&31;
  const int n = c>>4, ii = c&15;
  const size_t sbase = (size_t)(b*8 + n)*128;
  #pragma unroll
  for (int p=0; p<4; ++p){
    const int wf = wf0 + (p<<3) + tr, hh = h0 + tc;
    tile[(p<<3)+tr][tc] = src[((sbase + wf)*16 + ii)*256 + hh];
  }
  __syncthreads();
  const size_t dbase = (size_t)(b*128 + c)*256;
  #pragma unroll
  for (int p=0; p<4; ++p){
    const int hh = h0 + (p<<3) + tr, wf = wf0 + tc;
    dst[(dbase + hh)*WFP + wf] = tile[tc][(p<<3)+tr];
  }
}

// ---------------- IFFTW: irfft along W + s = h + y/256 -> st f16 ----------------
// grid 1024 = (b<<8)|h
__global__ __launch_bounds__(256, 2) void k_ifftw(const __half2* __restrict__ buf1,
    const f16* __restrict__ h2t, f16* __restrict__ st)
{
  __shared__ __half2 fb[64*256];
  const int t = threadIdx.x;
  const int b = blockIdx.x >> 8, h = blockIdx.x & 255;

  const int k = t;
  const int km = (256 - t) & 255;
  const bool lo = (k <= 128);
  const int kk = lo ? k : km;
  for (int it=0; it<64; ++it){
    const size_t pa = ((size_t)(b*128 + 2*it)*256 + h)*WFP;
    const float2 va = h2f2(buf1[pa + kk]);
    const float2 vb = h2f2(buf1[pa + 256*WFP + kk]);
    float2 Z = lo ? make_float2(va.x - vb.y, va.y + vb.x)
                  : make_float2(va.x + vb.y, vb.x - va.y);
    if (k == 0 || k == 128) Z = make_float2(va.x, vb.x);
    fb[(it<<8) + rev4(k)] = f2h2(Z.x, Z.y);
  }
  __syncthreads();

  fft256<1>(fb, 64, t, 256);   // y (unnormalized: 256x ortho)

  const size_t pg = (size_t)blockIdx.x*256 + t;
  const f16* hrow = h2t + pg*128;
  f16* srow = st + pg*128;
  #pragma unroll
  for (int i=0;i<16;++i){
    const f16x8 hv = ((const f16x8*)hrow)[i];
    f16x8 sv;
    #pragma unroll
    for (int j=0;j<4;++j){
      const float2 y = h2f2(fb[(i*4+j)*256 + t]);
      sv[2*j]   = (f16)((float)hv[2*j]   + y.x*0.00390625f);
      sv[2*j+1] = (f16)((float)hv[2*j+1] + y.y*0.00390625f);
    }
    ((f16x8*)srow)[i] = sv;
  }
}

// ---------------- GEMM2: out = p2 . s + p2b + x, MFMA ----------------
// grid 2048: tile M=128 o x N=128 pixels
__global__ __launch_bounds__(256) void k_gemm2(const f16* __restrict__ st, const float* __restrict__ w,
    const float* __restrict__ bias, const float* __restrict__ xg, float* __restrict__ outg)
{
  __shared__ f16 sa[128][72];
  __shared__ f16 wl[128][72];
  const int t = threadIdx.x, l = t&63, wid = t>>6;
  const int col = l&31;
  const size_t pg0 = (size_t)blockIdx.x * 128;
  f32x16 acc0=zero16(), acc1=zero16(), acc2=zero16(), acc3=zero16();
  for (int kk=0; kk<2; ++kk){
    __syncthreads();
    { const int row=t>>1, cb=(t&1)*32;
      const f16x8* src=(const f16x8*)(st + (pg0+row)*128 + kk*64 + cb);
      f16x8* dst=(f16x8*)&sa[row][cb];
      dst[0]=src[0]; dst[1]=src[1]; dst[2]=src[2]; dst[3]=src[3]; }
    { const int row=t>>1, cb=(t&1)*32;
      const float4* src=(const float4*)(w + row*128 + kk*64 + cb);
      #pragma unroll
      for(int i=0;i<8;++i){ const float4 v=src[i];
        f16x2 p0={(f16)v.x,(f16)v.y}, p1={(f16)v.z,(f16)v.w};
        *(f16x2*)&wl[row][cb+4*i]=p0; *(f16x2*)&wl[row][cb+4*i+2]=p1; } }
    __syncthreads();
    #pragma unroll
    for (int c=0;c<4;++c){
      const int ko = c*16 + (l>>5)*8;
      const f16x8 a  = *(const f16x8*)&wl[wid*32+col][ko];
      const f16x8 v0 = *(const f16x8*)&sa[  0+col][ko];
      const f16x8 v1 = *(const f16x8*)&sa[ 32+col][ko];
      const f16x8 v2 = *(const f16x8*)&sa[ 64+col][ko];
      const f16x8 v3 = *(const f16x8*)&sa[ 96+col][ko];
      acc0 = __builtin_amdgcn_mfma_f32_32x32x16_f16(a, v0, acc0, 0,0,0);
      acc1 = __builtin_amdgcn_mfma_f32_32x32x16_f16(a, v1, acc1, 0,0,0);
      acc2 = __builtin_amdgcn_mfma_f32_32x32x16_f16(a, v2, acc2, 0,0,0);
      acc3 = __builtin_amdgcn_mfma_f32_32x32x16_f16(a, v3, acc3, 0,0,0);
    }
  }
  const int b = (int)(pg0>>16), hw0 = (int)(pg0 & 65535);
  const int orow = wid*32 + 4*(l>>5);
  auto store2 = [&](const f32x16& A, int nt){
    #pragma unroll
    for (int r=0;r<16;++r){
      const int o = orow + (r&3) + 8*(r>>2);
      const size_t addr = (((size_t)(b*128+o))<<16) + (size_t)(hw0 + nt*32 + col);
      outg[addr] = A[r] + bias[o] + xg[addr];
    }
  };
  store2(acc0,0); store2(acc1,1); store2(acc2,2); store2(acc3,3);
}

extern "C" void kernel_launch(void* const* d_in, const int* in_sizes, int n_in,
                              void* d_out, int out_size, void* d_ws, size_t ws_size,
                              hipStream_t stream)
{
  (void)in_sizes; (void)n_in; (void)out_size;
  const float* x   = (const float*)d_in[0];
  const float* p1w = (const float*)d_in[1];
  const float* p1b = (const float*)d_in[2];
  const float* w1  = (const float*)d_in[3];
  const float* b1  = (const float*)d_in[4];
  const float* w2  = (const float*)d_in[5];
  const float* b2  = (const float*)d_in[6];
  const float* p2w = (const float*)d_in[7];
  const float* p2b = (const float*)d_in[8];
  float* out = (float*)d_out;

  const size_t BUF1_B = 4UL*128*256*WFP*4;   // 69,206,016  (ws, proven to fit)
  const size_t ST_B   = 262144UL*128*2;      // 67,108,864
  // Placement:
  //   ws   : xt [0,67.1M) (dead before fftw) -> buf1 [0,69.2M)
  //   d_out: buf2' (wf<128) [0,67.1M)  |  h^T f16 [67.1M,134.2M)  (exact fit)
  //   s^T  : ws tail if it fits, else buf2' region then d2d copy onto dead buf1
  f16*     xt   = (f16*)d_ws;
  __half2* buf1 = (__half2*)d_ws;
  __half2* buf2 = (__half2*)d_out;
  f16*     h2t  = (f16*)((char*)d_out + ST_B);
  const bool bigws = ws_size >= BUF1_B + ST_B;
  f16* st_w = bigws ? (f16*)((char*)d_ws + BUF1_B) : (f16*)d_out;
  f16* st_r = bigws ? st_w : (f16*)d_ws;

  k_tx      <<<dim3(4096),      dim3(256), 0, stream>>>(x, xt);
  k_gemm1   <<<dim3(2048),      dim3(256), 0, stream>>>(xt, p1w, p1b, h2t);
  k_fftw    <<<dim3(1024),      dim3(256), 0, stream>>>(h2t, buf1);
  k_t1      <<<dim3(4,1024,4),  dim3(256), 0, stream>>>(buf1, buf2);
  k_spec    <<<dim3(128,8,4),   dim3(256), 0, stream>>>(buf2, w1, b1, w2, b2);
  k_spec_nyq<<<dim3(8,4),       dim3(256), 0, stream>>>(buf1, w1, b1, w2, b2);
  k_t2      <<<dim3(4,1024,4),  dim3(256), 0, stream>>>(buf2, buf1);
  k_ifftw   <<<dim3(1024),      dim3(256), 0, stream>>>(buf1, h2t, st_w);
  if (!bigws) (void)hipMemcpyAsync(d_ws, d_out, ST_B, hipMemcpyDeviceToDevice, stream);
  k_gemm2   <<<dim3(2048),      dim3(256), 0, stream>>>(st_r, p2w, p2b, x, out);
}

// Round 4
// 458.930 us; speedup vs baseline: 3.2743x; 1.1192x over previous
//
#include <hip/hip_runtime.h>
#include <hip/hip_fp16.h>

#define DEVI __device__ __forceinline__

// B=4, C=128, H=W=256, Wf=129 (buf1 stride 132), nb=8, bs=16
#define WFP 132

typedef _Float16 f16;
typedef _Float16 f16x8 __attribute__((ext_vector_type(8)));
typedef float    f32x4  __attribute__((ext_vector_type(4)));
typedef float    f32x16 __attribute__((ext_vector_type(16)));

DEVI float2 cmul(float2 a, float2 b){ return make_float2(fmaf(a.x,b.x,-(a.y*b.y)), fmaf(a.x,b.y,a.y*b.x)); }
DEVI float2 h2f2(__half2 v){ return make_float2(__low2float(v), __high2float(v)); }
DEVI __half2 f2h2(float a, float b){ return __floats2half2_rn(a, b); }
DEVI int rev4(int k){ return ((k&3)<<6) | (((k>>2)&3)<<4) | (((k>>4)&3)<<2) | ((k>>6)&3); }
DEVI float gelu(float v){ return 0.5f*v*(1.0f + erff(v*0.70710678118654752f)); }
DEVI float sshrink(float v){ return v > 0.01f ? v-0.01f : (v < -0.01f ? v+0.01f : 0.0f); }
DEVI f32x16 zero16(){
  f32x16 z;
#pragma unroll
  for (int i=0;i<16;++i) z[i]=0.f;
  return z;
}

// In-place FFT over `rows` rows of 256 complex values (half2 in LDS, fp32 math).
// DIR=-1: forward DIF (natural in -> base-4 digit-reversed out).
// DIR=+1: inverse DIT (digit-reversed in -> natural out, UNNORMALIZED).
template<int DIR>
DEVI void fft256(__half2* d, int rows, int tid, int nthr){
  const int nbf = rows<<6;
  #pragma unroll
  for (int si=0; si<4; ++si){
    const int lq = (DIR<0) ? (6-2*si) : (2*si);
    const int q4 = 1<<lq;
    const int tws = 64>>lq;
    for (int u = tid; u < nbf; u += nthr){
      const int row = u>>6, w = u&63;
      const int j = w & (q4-1);
      const int blk = w >> lq;
      const int base = (row<<8) + (blk<<(lq+2)) + j;
      const int e = j*tws;
      float sn, cs;
      __sincosf((float)(DIR*e) * 0.0245436926061703f, &sn, &cs);
      const float2 w1 = make_float2(cs, sn);
      const float2 w2 = make_float2(cs*cs - sn*sn, 2.f*cs*sn);
      const float2 w3 = cmul(w2, w1);
      if (DIR < 0){
        float2 x0 = h2f2(d[base]);
        float2 x1 = h2f2(d[base+q4]);
        float2 x2 = h2f2(d[base+2*q4]);
        float2 x3 = h2f2(d[base+3*q4]);
        float2 t0 = make_float2(x0.x+x2.x, x0.y+x2.y);
        float2 t1 = make_float2(x0.x-x2.x, x0.y-x2.y);
        float2 t2 = make_float2(x1.x+x3.x, x1.y+x3.y);
        float2 t3 = make_float2(x1.y-x3.y, x3.x-x1.x);
        float2 u1 = cmul(make_float2(t1.x+t3.x, t1.y+t3.y), w1);
        float2 u2 = cmul(make_float2(t0.x-t2.x, t0.y-t2.y), w2);
        float2 u3 = cmul(make_float2(t1.x-t3.x, t1.y-t3.y), w3);
        d[base]      = f2h2(t0.x+t2.x, t0.y+t2.y);
        d[base+q4]   = f2h2(u1.x, u1.y);
        d[base+2*q4] = f2h2(u2.x, u2.y);
        d[base+3*q4] = f2h2(u3.x, u3.y);
      } else {
        float2 x0  = h2f2(d[base]);
        float2 b1v = cmul(h2f2(d[base+q4]),   w1);
        float2 b2v = cmul(h2f2(d[base+2*q4]), w2);
        float2 b3v = cmul(h2f2(d[base+3*q4]), w3);
        float2 t0 = make_float2(x0.x+b2v.x, x0.y+b2v.y);
        float2 t1 = make_float2(x0.x-b2v.x, x0.y-b2v.y);
        float2 t2 = make_float2(b1v.x+b3v.x, b1v.y+b3v.y);
        float2 t3 = make_float2(-(b1v.y-b3v.y), b1v.x-b3v.x);
        d[base]      = f2h2(t0.x+t2.x, t0.y+t2.y);
        d[base+q4]   = f2h2(t1.x+t3.x, t1.y+t3.y);
        d[base+2*q4] = f2h2(t0.x-t2.x, t0.y-t2.y);
        d[base+3*q4] = f2h2(t1.x-t3.x, t1.y-t3.y);
      }
    }
    __syncthreads();
  }
}

// ---------------- GEMM1 (fused transpose): h^T[pg][co] = gelu(p1w.x + p1b) ----------------
// grid 2048: tile M=128 pixels x N=128 co, K=128 in 2 halves. 4 waves.
// x staged transposed into LDS [px][c] half2 (stride 17 dw); B-frags (p1w) from global (L2-hot).
__global__ __launch_bounds__(256) void k_gemm1(const float* __restrict__ xg, const float* __restrict__ w,
    const float* __restrict__ bias, f16* __restrict__ h2t)
{
  __shared__ __half2 xa[128*34];   // [px][34 half2] = 64 f16 data + 4 pad
  f16* xaF = (f16*)xa;
  const int* xaI = (const int*)xa;
  const int t = threadIdx.x, l = t&63, wid = t>>6;
  const size_t pg0 = (size_t)blockIdx.x * 128;
  const int b = (int)(pg0>>16), hw0 = (int)(pg0&65535);
  f32x16 acc[4];
  #pragma unroll
  for (int nt=0;nt<4;++nt) acc[nt]=zero16();
  const int c0 = t>>4, w4 = (t&15)*4;
  for (int kk=0; kk<2; ++kk){
    __syncthreads();
    #pragma unroll
    for (int p2=0; p2<2; ++p2)
      #pragma unroll
      for (int i=0;i<4;++i){
        const int c = c0 + i*16;          // 0..63 within K-half
        const int px = w4 + p2*64;
        const float4 v = *(const float4*)(xg + (((size_t)(b*128 + kk*64 + c))<<16) + hw0 + px);
        xaF[(px+0)*68 + c] = (f16)v.x;
        xaF[(px+1)*68 + c] = (f16)v.y;
        xaF[(px+2)*68 + c] = (f16)v.z;
        xaF[(px+3)*68 + c] = (f16)v.w;
      }
    __syncthreads();
    #pragma unroll
    for (int kq=0; kq<4; ++kq){
      f16x8 A;
      { int4 tmp;
        const int ab = (wid*32 + (l&31))*34 + kq*8 + (l>>5)*4;
        tmp.x=xaI[ab]; tmp.y=xaI[ab+1]; tmp.z=xaI[ab+2]; tmp.w=xaI[ab+3];
        A = __builtin_bit_cast(f16x8, tmp); }
      #pragma unroll
      for (int nt=0; nt<4; ++nt){
        const int co = nt*32 + (l&31);
        const float* wp = w + co*128 + kk*64 + kq*16 + (l>>5)*8;
        const float4 w0 = *(const float4*)wp;
        const float4 w1v = *(const float4*)(wp+4);
        const f16x8 Bf = {(f16)w0.x,(f16)w0.y,(f16)w0.z,(f16)w0.w,
                          (f16)w1v.x,(f16)w1v.y,(f16)w1v.z,(f16)w1v.w};
        acc[nt] = __builtin_amdgcn_mfma_f32_32x32x16_f16(A, Bf, acc[nt], 0,0,0);
      }
    }
  }
  #pragma unroll
  for (int nt=0;nt<4;++nt){
    const int co = nt*32 + (l&31);
    const float bi = bias[co];
    #pragma unroll
    for (int r=0;r<16;++r){
      const int px = wid*32 + (r&3) + 8*(r>>2) + 4*(l>>5);
      h2t[(pg0+(size_t)px)*128 + co] = (f16)gelu(acc[nt][r] + bi);
    }
  }
}

// ---------------- FFTW: rfft along W of h rows -> buf1 ----------------
// grid 1024 = (b<<8)|h, block 256 (thread = pixel w)
__global__ __launch_bounds__(256, 2) void k_fftw(const f16* __restrict__ h2t, __half2* __restrict__ buf1)
{
  __shared__ __half2 fb[64*256];
  const int t = threadIdx.x;
  const int b = blockIdx.x >> 8, h = blockIdx.x & 255;
  const size_t pg = (size_t)blockIdx.x*256 + t;
  const f16* row = h2t + pg*128;
  #pragma unroll
  for (int i=0;i<16;++i){
    const f16x8 v = ((const f16x8*)row)[i];
    const __half2* vp = (const __half2*)&v;
    #pragma unroll
    for (int j=0;j<4;++j) fb[(i*4+j)*256 + t] = vp[j];
  }
  __syncthreads();

  fft256<-1>(fb, 64, t, 256);

  for (int it=0; it<32; ++it){
    const int idx = (it<<8) + t;
    const int r = idx>>7, k = idx&127;
    const float2 zk = h2f2(fb[(r<<8) + rev4(k)]);
    const float2 zm = h2f2(fb[(r<<8) + rev4((256-k)&255)]);
    const float ar = (zk.x+zm.x)*0.03125f, ai = (zk.y-zm.y)*0.03125f;
    const float br = (zk.y+zm.y)*0.03125f, bi = (zm.x-zk.x)*0.03125f;
    const size_t pa = ((size_t)(b*128 + 2*r)*256 + h)*WFP + k;
    buf1[pa]           = f2h2(ar, ai);
    buf1[pa + 256*WFP] = f2h2(br, bi);
  }
  if (t < 64){
    const int r = t;
    const float2 zk = h2f2(fb[(r<<8) + rev4(128)]);
    const size_t pa = ((size_t)(b*128 + 2*r)*256 + h)*WFP + 128;
    buf1[pa]           = f2h2(zk.x*0.0625f, 0.f);
    buf1[pa + 256*WFP] = f2h2(zk.y*0.0625f, 0.f);
  }
}

// ---------------- T1: [B][C][H][132] cols 0..127 -> [B][n][wf][i][H] ----------------
// grid (4, 1024, 4)
__global__ __launch_bounds__(256) void k_t1(const __half2* __restrict__ src, __half2* __restrict__ dst)
{
  __shared__ __half2 tile[32][33];
  const int t = threadIdx.x;
  const int wt = blockIdx.x;
  const int ht = blockIdx.y & 7, c = blockIdx.y >> 3, b = blockIdx.z;
  const int h0 = ht<<5, wf0 = wt<<5;
  const int tr = t>>5, tc = t&31;
  const size_t sbase = (size_t)(b*128 + c)*256;
  #pragma unroll
  for (int p=0; p<4; ++p){
    const int hh = h0 + (p<<3) + tr, wf = wf0 + tc;
    tile[(p<<3)+tr][tc] = src[(sbase + hh)*WFP + wf];
  }
  __syncthreads();
  const int n = c>>4, ii = c&15;
  const size_t dbase = (size_t)(b*8 + n)*128;
  #pragma unroll
  for (int p=0; p<4; ++p){
    const int wf = wf0 + (p<<3) + tr, hh = h0 + tc;
    dst[((dbase + wf)*16 + ii)*256 + hh] = tile[tc][(p<<3)+tr];
  }
}

// ---------------- spec body v2: FFT along H + complex block-MLP (MFMA) + inverse ----------------
// data: [16 ch][256 pts] half2.  xp: [256 pts][17] half2 (K-interleaved MLP operand).
// o1b: [4 waves][16][17] half2 bounce for layer-1 output.
DEVI void spec_body(__half2* data, __half2* xp, __half2* o1b, int n,
                    const float* __restrict__ w1, const float* __restrict__ b1,
                    const float* __restrict__ w2, const float* __restrict__ b2, int t)
{
  fft256<-1>(data, 16, t, 256);

  const int l = t&63, wid = t>>6;
  const int o = l&15, kb = l>>4;

  // B-fragments (lane: col=o, k = kb*8+j; k even -> re-input weight row, k odd -> im)
  // layer1 scaled by 1/16 (ortho fwd H-FFT norm folded in).
  f16x8 B1R, B1I, B2R, B2I;
  #pragma unroll
  for (int j=0;j<8;++j){
    const int i = kb*4 + (j>>1);
    const float a1r = w1[(n*16+i)*16+o], a1i = w1[2048 + (n*16+i)*16+o];
    const float a2r = w2[(n*16+i)*16+o], a2i = w2[2048 + (n*16+i)*16+o];
    B1R[j] = (f16)(((j&1) ? -a1i : a1r) * 0.0625f);
    B1I[j] = (f16)(((j&1) ?  a1r : a1i) * 0.0625f);
    B2R[j] = (f16)((j&1) ? -a2i : a2r);
    B2I[j] = (f16)((j&1) ?  a2r : a2i);
  }
  const float b1r = b1[n*16+o],     b1i = b1[128 + n*16+o];
  const float b2r = b2[n*16+o],     b2i = b2[128 + n*16+o];
  const f32x4 cR1 = {b1r,b1r,b1r,b1r}, cI1 = {b1i,b1i,b1i,b1i};
  const f32x4 cR2 = {b2r,b2r,b2r,b2r}, cI2 = {b2i,b2i,b2i,b2i};

  // transpose data columns into xp rows (raw half2 copy; K stays interleaved re/im)
  #pragma unroll
  for (int i=0;i<16;++i) xp[t*17 + i] = data[(i<<8) + t];
  __syncthreads();

  const int* xpI  = (const int*)xp;
  const int* o1bI = (const int*)o1b;
  __half2*  ob    = o1b + wid*(16*17);

  #pragma unroll
  for (int tt=0; tt<4; ++tt){
    const int p0 = wid*64 + tt*16;
    f16x8 A1;
    { int4 tmp;
      const int ab = (p0 + o)*17 + kb*4;
      tmp.x=xpI[ab]; tmp.y=xpI[ab+1]; tmp.z=xpI[ab+2]; tmp.w=xpI[ab+3];
      A1 = __builtin_bit_cast(f16x8, tmp); }
    f32x4 aR = __builtin_amdgcn_mfma_f32_16x16x32_f16(A1, B1R, cR1, 0,0,0);
    f32x4 aI = __builtin_amdgcn_mfma_f32_16x16x32_f16(A1, B1I, cI1, 0,0,0);
    #pragma unroll
    for (int r=0;r<4;++r)
      ob[(kb*4+r)*17 + o] = f2h2(fmaxf(aR[r],0.f), fmaxf(aI[r],0.f));
    f16x8 A2;
    { int4 tmp;
      const int ab = wid*(16*17) + o*17 + kb*4;
      tmp.x=o1bI[ab]; tmp.y=o1bI[ab+1]; tmp.z=o1bI[ab+2]; tmp.w=o1bI[ab+3];
      A2 = __builtin_bit_cast(f16x8, tmp); }
    f32x4 oR = __builtin_amdgcn_mfma_f32_16x16x32_f16(A2, B2R, cR2, 0,0,0);
    f32x4 oI = __builtin_amdgcn_mfma_f32_16x16x32_f16(A2, B2I, cI2, 0,0,0);
    #pragma unroll
    for (int r=0;r<4;++r)
      xp[(p0 + kb*4 + r)*17 + o] = f2h2(sshrink(oR[r]), sshrink(oI[r]));
  }
  __syncthreads();

  // xp rows -> data columns
  #pragma unroll
  for (int i=0;i<16;++i) data[(i<<8) + t] = xp[t*17 + i];
  __syncthreads();

  fft256<1>(data, 16, t, 256);
}

// grid (128, 8, 4): wf<128 from buf2
__global__ __launch_bounds__(256) void k_spec(__half2* __restrict__ buf2,
    const float* __restrict__ w1, const float* __restrict__ b1,
    const float* __restrict__ w2, const float* __restrict__ b2)
{
  __shared__ __half2 data[16*256];
  __shared__ __half2 xp[256*17];
  __shared__ __half2 o1b[4*16*17];
  const int t = threadIdx.x;
  const int wf = blockIdx.x, n = blockIdx.y, b = blockIdx.z;
  __half2* chunk = buf2 + ((size_t)((b*8 + n)*128 + wf) << 12);
  #pragma unroll
  for (int p=0; p<4; ++p) ((float4*)data)[(p<<8)+t] = ((const float4*)chunk)[(p<<8)+t];
  __syncthreads();
  spec_body(data, xp, o1b, n, w1,b1,w2,b2, t);
  #pragma unroll
  for (int p=0; p<4; ++p) ((float4*)chunk)[(p<<8)+t] = ((const float4*)data)[(p<<8)+t];
}

// grid (8, 4): wf==128 (Nyquist) gathered straight from buf1 col 128
__global__ __launch_bounds__(256) void k_spec_nyq(__half2* __restrict__ buf1,
    const float* __restrict__ w1, const float* __restrict__ b1,
    const float* __restrict__ w2, const float* __restrict__ b2)
{
  __shared__ __half2 data[16*256];
  __shared__ __half2 xp[256*17];
  __shared__ __half2 o1b[4*16*17];
  const int t = threadIdx.x;
  const int n = blockIdx.x, b = blockIdx.y;
  #pragma unroll
  for (int i=0;i<16;++i)
    data[(i<<8) + t] = buf1[((size_t)(b*128 + n*16 + i)*256 + t)*WFP + 128];
  __syncthreads();
  spec_body(data, xp, o1b, n, w1,b1,w2,b2, t);
  #pragma unroll
  for (int i=0;i<16;++i)
    buf1[((size_t)(b*128 + n*16 + i)*256 + t)*WFP + 128] = data[(i<<8) + t];
}

// ---------------- T2: [B][n][wf][i][H] -> [B][C][H][132] cols 0..127 ----------------
__global__ __launch_bounds__(256) void k_t2(const __half2* __restrict__ src, __half2* __restrict__ dst)
{
  __shared__ __half2 tile[32][33];
  const int t = threadIdx.x;
  const int wt = blockIdx.x;
  const int ht = blockIdx.y & 7, c = blockIdx.y >> 3, b = blockIdx.z;
  const int h0 = ht<<5, wf0 = wt<<5;
  const int tr = t>>5, tc = t&31;
  const int n = c>>4, ii = c&15;
  const size_t sbase = (size_t)(b*8 + n)*128;
  #pragma unroll
  for (int p=0; p<4; ++p){
    const int wf = wf0 + (p<<3) + tr, hh = h0 + tc;
    tile[(p<<3)+tr][tc] = src[((sbase + wf)*16 + ii)*256 + hh];
  }
  __syncthreads();
  const size_t dbase = (size_t)(b*128 + c)*256;
  #pragma unroll
  for (int p=0; p<4; ++p){
    const int hh = h0 + (p<<3) + tr, wf = wf0 + tc;
    dst[(dbase + hh)*WFP + wf] = tile[tc][(p<<3)+tr];
  }
}

// ---------------- IFFTW: irfft along W + s = h + y/256 -> st f16 ----------------
// grid 1024 = (b<<8)|h
__global__ __launch_bounds__(256, 2) void k_ifftw(const __half2* __restrict__ buf1,
    const f16* __restrict__ h2t, f16* __restrict__ st)
{
  __shared__ __half2 fb[64*256];
  const int t = threadIdx.x;
  const int b = blockIdx.x >> 8, h = blockIdx.x & 255;

  const int k = t;
  const int km = (256 - t) & 255;
  const bool lo = (k <= 128);
  const int kk = lo ? k : km;
  for (int it=0; it<64; ++it){
    const size_t pa = ((size_t)(b*128 + 2*it)*256 + h)*WFP;
    const float2 va = h2f2(buf1[pa + kk]);
    const float2 vb = h2f2(buf1[pa + 256*WFP + kk]);
    float2 Z = lo ? make_float2(va.x - vb.y, va.y + vb.x)
                  : make_float2(va.x + vb.y, vb.x - va.y);
    if (k == 0 || k == 128) Z = make_float2(va.x, vb.x);
    fb[(it<<8) + rev4(k)] = f2h2(Z.x, Z.y);
  }
  __syncthreads();

  fft256<1>(fb, 64, t, 256);   // y (unnormalized: 256x ortho)

  const size_t pg = (size_t)blockIdx.x*256 + t;
  const f16* hrow = h2t + pg*128;
  f16* srow = st + pg*128;
  #pragma unroll
  for (int i=0;i<16;++i){
    const f16x8 hv = ((const f16x8*)hrow)[i];
    f16x8 sv;
    #pragma unroll
    for (int j=0;j<4;++j){
      const float2 y = h2f2(fb[(i*4+j)*256 + t]);
      sv[2*j]   = (f16)((float)hv[2*j]   + y.x*0.00390625f);
      sv[2*j+1] = (f16)((float)hv[2*j+1] + y.y*0.00390625f);
    }
    ((f16x8*)srow)[i] = sv;
  }
}

// ---------------- GEMM2: out = p2 . s + p2b + x, MFMA ----------------
// grid 2048: tile M=128 o x N=128 pixels
__global__ __launch_bounds__(256) void k_gemm2(const f16* __restrict__ st, const float* __restrict__ w,
    const float* __restrict__ bias, const float* __restrict__ xg, float* __restrict__ outg)
{
  __shared__ f16 sa[128][72];
  __shared__ f16 wl[128][72];
  typedef _Float16 f16x2 __attribute__((ext_vector_type(2)));
  const int t = threadIdx.x, l = t&63, wid = t>>6;
  const int col = l&31;
  const size_t pg0 = (size_t)blockIdx.x * 128;
  f32x16 acc0=zero16(), acc1=zero16(), acc2=zero16(), acc3=zero16();
  for (int kk=0; kk<2; ++kk){
    __syncthreads();
    { const int row=t>>1, cb=(t&1)*32;
      const f16x8* src=(const f16x8*)(st + (pg0+row)*128 + kk*64 + cb);
      f16x8* dst=(f16x8*)&sa[row][cb];
      dst[0]=src[0]; dst[1]=src[1]; dst[2]=src[2]; dst[3]=src[3]; }
    { const int row=t>>1, cb=(t&1)*32;
      const float4* src=(const float4*)(w + row*128 + kk*64 + cb);
      #pragma unroll
      for(int i=0;i<8;++i){ const float4 v=src[i];
        f16x2 p0={(f16)v.x,(f16)v.y}, p1={(f16)v.z,(f16)v.w};
        *(f16x2*)&wl[row][cb+4*i]=p0; *(f16x2*)&wl[row][cb+4*i+2]=p1; } }
    __syncthreads();
    #pragma unroll
    for (int c=0;c<4;++c){
      const int ko = c*16 + (l>>5)*8;
      const f16x8 a  = *(const f16x8*)&wl[wid*32+col][ko];
      const f16x8 v0 = *(const f16x8*)&sa[  0+col][ko];
      const f16x8 v1 = *(const f16x8*)&sa[ 32+col][ko];
      const f16x8 v2 = *(const f16x8*)&sa[ 64+col][ko];
      const f16x8 v3 = *(const f16x8*)&sa[ 96+col][ko];
      acc0 = __builtin_amdgcn_mfma_f32_32x32x16_f16(a, v0, acc0, 0,0,0);
      acc1 = __builtin_amdgcn_mfma_f32_32x32x16_f16(a, v1, acc1, 0,0,0);
      acc2 = __builtin_amdgcn_mfma_f32_32x32x16_f16(a, v2, acc2, 0,0,0);
      acc3 = __builtin_amdgcn_mfma_f32_32x32x16_f16(a, v3, acc3, 0,0,0);
    }
  }
  const int b = (int)(pg0>>16), hw0 = (int)(pg0 & 65535);
  const int orow = wid*32 + 4*(l>>5);
  auto store2 = [&](const f32x16& A, int nt){
    #pragma unroll
    for (int r=0;r<16;++r){
      const int o = orow + (r&3) + 8*(r>>2);
      const size_t addr = (((size_t)(b*128+o))<<16) + (size_t)(hw0 + nt*32 + col);
      outg[addr] = A[r] + bias[o] + xg[addr];
    }
  };
  store2(acc0,0); store2(acc1,1); store2(acc2,2); store2(acc3,3);
}

extern "C" void kernel_launch(void* const* d_in, const int* in_sizes, int n_in,
                              void* d_out, int out_size, void* d_ws, size_t ws_size,
                              hipStream_t stream)
{
  (void)in_sizes; (void)n_in; (void)out_size;
  const float* x   = (const float*)d_in[0];
  const float* p1w = (const float*)d_in[1];
  const float* p1b = (const float*)d_in[2];
  const float* w1  = (const float*)d_in[3];
  const float* b1  = (const float*)d_in[4];
  const float* w2  = (const float*)d_in[5];
  const float* b2  = (const float*)d_in[6];
  const float* p2w = (const float*)d_in[7];
  const float* p2b = (const float*)d_in[8];
  float* out = (float*)d_out;

  const size_t BUF1_B = 4UL*128*256*WFP*4;   // 69,206,016  (ws, proven to fit)
  const size_t ST_B   = 262144UL*128*2;      // 67,108,864
  // Placement:
  //   ws   : buf1 [0,69.2M)
  //   d_out: buf2' (wf<128) [0,67.1M)  |  h^T f16 [67.1M,134.2M)  (exact fit)
  //   s^T  : ws tail if it fits, else buf2' region then d2d copy onto dead buf1
  __half2* buf1 = (__half2*)d_ws;
  __half2* buf2 = (__half2*)d_out;
  f16*     h2t  = (f16*)((char*)d_out + ST_B);
  const bool bigws = ws_size >= BUF1_B + ST_B;
  f16* st_w = bigws ? (f16*)((char*)d_ws + BUF1_B) : (f16*)d_out;
  f16* st_r = bigws ? st_w : (f16*)d_ws;

  k_gemm1   <<<dim3(2048),      dim3(256), 0, stream>>>(x, p1w, p1b, h2t);
  k_fftw    <<<dim3(1024),      dim3(256), 0, stream>>>(h2t, buf1);
  k_t1      <<<dim3(4,1024,4),  dim3(256), 0, stream>>>(buf1, buf2);
  k_spec    <<<dim3(128,8,4),   dim3(256), 0, stream>>>(buf2, w1, b1, w2, b2);
  k_spec_nyq<<<dim3(8,4),       dim3(256), 0, stream>>>(buf1, w1, b1, w2, b2);
  k_t2      <<<dim3(4,1024,4),  dim3(256), 0, stream>>>(buf2, buf1);
  k_ifftw   <<<dim3(1024),      dim3(256), 0, stream>>>(buf1, h2t, st_w);
  if (!bigws) (void)hipMemcpyAsync(d_ws, d_out, ST_B, hipMemcpyDeviceToDevice, stream);
  k_gemm2   <<<dim3(2048),      dim3(256), 0, stream>>>(st_r, p2w, p2b, x, out);
}

// Round 5
// 411.870 us; speedup vs baseline: 3.6484x; 1.1143x over previous
//
#include <hip/hip_runtime.h>
#include <hip/hip_fp16.h>

#define DEVI __device__ __forceinline__

// B=4, C=128, H=W=256, Wf=129 (buf1 stride 132), nb=8, bs=16
#define WFP 132

typedef _Float16 f16;
typedef _Float16 f16x8 __attribute__((ext_vector_type(8)));
typedef _Float16 f16x4 __attribute__((ext_vector_type(4)));
typedef float    f32x4  __attribute__((ext_vector_type(4)));
typedef float    f32x16 __attribute__((ext_vector_type(16)));

DEVI float2 cmul(float2 a, float2 b){ return make_float2(fmaf(a.x,b.x,-(a.y*b.y)), fmaf(a.x,b.y,a.y*b.x)); }
DEVI float2 h2f2(__half2 v){ return make_float2(__low2float(v), __high2float(v)); }
DEVI __half2 f2h2(float a, float b){ return __floats2half2_rn(a, b); }
DEVI int rev4(int k){ return ((k&3)<<6) | (((k>>2)&3)<<4) | (((k>>4)&3)<<2) | ((k>>6)&3); }
DEVI float gelu(float v){ return 0.5f*v*(1.0f + erff(v*0.70710678118654752f)); }
DEVI float sshrink(float v){ return v > 0.01f ? v-0.01f : (v < -0.01f ? v+0.01f : 0.0f); }
DEVI f32x16 zero16(){
  f32x16 z;
#pragma unroll
  for (int i=0;i<16;++i) z[i]=0.f;
  return z;
}

// In-place FFT over `rows` rows of 256 complex values (half2 in LDS, fp32 math).
// DIR=-1: forward DIF (natural in -> base-4 digit-reversed out).
// DIR=+1: inverse DIT (digit-reversed in -> natural out, UNNORMALIZED).
template<int DIR>
DEVI void fft256(__half2* d, int rows, int tid, int nthr){
  const int nbf = rows<<6;
  #pragma unroll
  for (int si=0; si<4; ++si){
    const int lq = (DIR<0) ? (6-2*si) : (2*si);
    const int q4 = 1<<lq;
    const int tws = 64>>lq;
    for (int u = tid; u < nbf; u += nthr){
      const int row = u>>6, w = u&63;
      const int j = w & (q4-1);
      const int blk = w >> lq;
      const int base = (row<<8) + (blk<<(lq+2)) + j;
      const int e = j*tws;
      float sn, cs;
      __sincosf((float)(DIR*e) * 0.0245436926061703f, &sn, &cs);
      const float2 w1 = make_float2(cs, sn);
      const float2 w2 = make_float2(cs*cs - sn*sn, 2.f*cs*sn);
      const float2 w3 = cmul(w2, w1);
      if (DIR < 0){
        float2 x0 = h2f2(d[base]);
        float2 x1 = h2f2(d[base+q4]);
        float2 x2 = h2f2(d[base+2*q4]);
        float2 x3 = h2f2(d[base+3*q4]);
        float2 t0 = make_float2(x0.x+x2.x, x0.y+x2.y);
        float2 t1 = make_float2(x0.x-x2.x, x0.y-x2.y);
        float2 t2 = make_float2(x1.x+x3.x, x1.y+x3.y);
        float2 t3 = make_float2(x1.y-x3.y, x3.x-x1.x);
        float2 u1 = cmul(make_float2(t1.x+t3.x, t1.y+t3.y), w1);
        float2 u2 = cmul(make_float2(t0.x-t2.x, t0.y-t2.y), w2);
        float2 u3 = cmul(make_float2(t1.x-t3.x, t1.y-t3.y), w3);
        d[base]      = f2h2(t0.x+t2.x, t0.y+t2.y);
        d[base+q4]   = f2h2(u1.x, u1.y);
        d[base+2*q4] = f2h2(u2.x, u2.y);
        d[base+3*q4] = f2h2(u3.x, u3.y);
      } else {
        float2 x0  = h2f2(d[base]);
        float2 b1v = cmul(h2f2(d[base+q4]),   w1);
        float2 b2v = cmul(h2f2(d[base+2*q4]), w2);
        float2 b3v = cmul(h2f2(d[base+3*q4]), w3);
        float2 t0 = make_float2(x0.x+b2v.x, x0.y+b2v.y);
        float2 t1 = make_float2(x0.x-b2v.x, x0.y-b2v.y);
        float2 t2 = make_float2(b1v.x+b3v.x, b1v.y+b3v.y);
        float2 t3 = make_float2(-(b1v.y-b3v.y), b1v.x-b3v.x);
        d[base]      = f2h2(t0.x+t2.x, t0.y+t2.y);
        d[base+q4]   = f2h2(t1.x+t3.x, t1.y+t3.y);
        d[base+2*q4] = f2h2(t0.x-t2.x, t0.y-t2.y);
        d[base+3*q4] = f2h2(t1.x-t3.x, t1.y-t3.y);
      }
    }
    __syncthreads();
  }
}

// ---------------- GEMM1 (fused transpose, fixed staging): h^T[pg][co] = gelu(p1w.x + p1b) ----------------
// grid 2048: tile M=128 pixels x N=128 co, K=128 in 2 halves. 4 waves.
// xa: [px][c] f16, row stride 72 (144B, 16B-aligned).  wl: [co][c] f16, stride 136 (272B), staged once.
__global__ __launch_bounds__(256) void k_gemm1(const float* __restrict__ xg, const float* __restrict__ w,
    const float* __restrict__ bias, f16* __restrict__ h2t)
{
  __shared__ f16 wl[128][136];
  __shared__ f16 xa[128][72];
  const int t = threadIdx.x, l = t&63, wid = t>>6;
  const size_t pg0 = (size_t)blockIdx.x * 128;
  const int b = (int)(pg0>>16), hw0 = (int)(pg0&65535);

  // ---- stage w (16384 f32) once, flat-coalesced float4, b64 f16 writes ----
  #pragma unroll
  for (int i=0;i<16;++i){
    const int f4 = i*256 + t;              // float4 index
    const int row = f4>>5, col = (f4&31)*4;
    const float4 v = ((const float4*)w)[f4];
    const f16x4 pk = {(f16)v.x,(f16)v.y,(f16)v.z,(f16)v.w};
    *(f16x4*)&wl[row][col] = pk;
  }

  f32x16 acc[4];
  #pragma unroll
  for (int nt=0;nt<4;++nt) acc[nt]=zero16();

  const int px = t&127, cq = t>>7;
  for (int kk=0; kk<2; ++kk){
    __syncthreads();
    // ---- stage x^T: scalar f32 coalesced (lane=px), channel-quad -> one b64 write ----
    #pragma unroll
    for (int i=0;i<8;++i){
      const int c4 = (cq + 2*i)*4;         // 0..60 step 4 within this K-half
      const float* xp = xg + (((size_t)(b*128 + kk*64 + c4))<<16) + hw0 + px;
      const float v0 = xp[0];
      const float v1 = xp[65536];
      const float v2 = xp[131072];
      const float v3 = xp[196608];
      const f16x4 pk = {(f16)v0,(f16)v1,(f16)v2,(f16)v3};
      *(f16x4*)&xa[px][c4] = pk;
    }
    __syncthreads();
    #pragma unroll
    for (int kq=0; kq<4; ++kq){
      const f16x8 A = *(const f16x8*)&xa[wid*32 + (l&31)][kq*16 + (l>>5)*8];
      #pragma unroll
      for (int nt=0; nt<4; ++nt){
        const f16x8 Bf = *(const f16x8*)&wl[nt*32 + (l&31)][kk*64 + kq*16 + (l>>5)*8];
        acc[nt] = __builtin_amdgcn_mfma_f32_32x32x16_f16(A, Bf, acc[nt], 0,0,0);
      }
    }
  }
  #pragma unroll
  for (int nt=0;nt<4;++nt){
    const int co = nt*32 + (l&31);
    const float bi = bias[co];
    #pragma unroll
    for (int r=0;r<16;++r){
      const int p = wid*32 + (r&3) + 8*(r>>2) + 4*(l>>5);
      h2t[(pg0+(size_t)p)*128 + co] = (f16)gelu(acc[nt][r] + bi);
    }
  }
}

// ---------------- FFTW: rfft along W of h rows -> buf1 ----------------
// grid 1024 = (b<<8)|h, block 256 (thread = pixel w)
__global__ __launch_bounds__(256, 2) void k_fftw(const f16* __restrict__ h2t, __half2* __restrict__ buf1)
{
  __shared__ __half2 fb[64*256];
  const int t = threadIdx.x;
  const int b = blockIdx.x >> 8, h = blockIdx.x & 255;
  const size_t pg = (size_t)blockIdx.x*256 + t;
  const f16* row = h2t + pg*128;
  #pragma unroll
  for (int i=0;i<16;++i){
    const f16x8 v = ((const f16x8*)row)[i];
    const __half2* vp = (const __half2*)&v;
    #pragma unroll
    for (int j=0;j<4;++j) fb[(i*4+j)*256 + t] = vp[j];
  }
  __syncthreads();

  fft256<-1>(fb, 64, t, 256);

  for (int it=0; it<32; ++it){
    const int idx = (it<<8) + t;
    const int r = idx>>7, k = idx&127;
    const float2 zk = h2f2(fb[(r<<8) + rev4(k)]);
    const float2 zm = h2f2(fb[(r<<8) + rev4((256-k)&255)]);
    const float ar = (zk.x+zm.x)*0.03125f, ai = (zk.y-zm.y)*0.03125f;
    const float br = (zk.y+zm.y)*0.03125f, bi = (zm.x-zk.x)*0.03125f;
    const size_t pa = ((size_t)(b*128 + 2*r)*256 + h)*WFP + k;
    buf1[pa]           = f2h2(ar, ai);
    buf1[pa + 256*WFP] = f2h2(br, bi);
  }
  if (t < 64){
    const int r = t;
    const float2 zk = h2f2(fb[(r<<8) + rev4(128)]);
    const size_t pa = ((size_t)(b*128 + 2*r)*256 + h)*WFP + 128;
    buf1[pa]           = f2h2(zk.x*0.0625f, 0.f);
    buf1[pa + 256*WFP] = f2h2(zk.y*0.0625f, 0.f);
  }
}

// ---------------- T1: [B][C][H][132] cols 0..127 -> [B][n][wf][i][H] ----------------
// grid (4, 1024, 4)
__global__ __launch_bounds__(256) void k_t1(const __half2* __restrict__ src, __half2* __restrict__ dst)
{
  __shared__ __half2 tile[32][33];
  const int t = threadIdx.x;
  const int wt = blockIdx.x;
  const int ht = blockIdx.y & 7, c = blockIdx.y >> 3, b = blockIdx.z;
  const int h0 = ht<<5, wf0 = wt<<5;
  const int tr = t>>5, tc = t&31;
  const size_t sbase = (size_t)(b*128 + c)*256;
  #pragma unroll
  for (int p=0; p<4; ++p){
    const int hh = h0 + (p<<3) + tr, wf = wf0 + tc;
    tile[(p<<3)+tr][tc] = src[(sbase + hh)*WFP + wf];
  }
  __syncthreads();
  const int n = c>>4, ii = c&15;
  const size_t dbase = (size_t)(b*8 + n)*128;
  #pragma unroll
  for (int p=0; p<4; ++p){
    const int wf = wf0 + (p<<3) + tr, hh = h0 + tc;
    dst[((dbase + wf)*16 + ii)*256 + hh] = tile[tc][(p<<3)+tr];
  }
}

// ---------------- spec body v2: FFT along H + complex block-MLP (MFMA) + inverse ----------------
// data: [16 ch][256 pts] half2.  xp: [256 pts][17] half2 (K-interleaved MLP operand).
// o1b: [4 waves][16][17] half2 bounce for layer-1 output.
DEVI void spec_body(__half2* data, __half2* xp, __half2* o1b, int n,
                    const float* __restrict__ w1, const float* __restrict__ b1,
                    const float* __restrict__ w2, const float* __restrict__ b2, int t)
{
  fft256<-1>(data, 16, t, 256);

  const int l = t&63, wid = t>>6;
  const int o = l&15, kb = l>>4;

  // B-fragments (lane: col=o, k = kb*8+j; k even -> re-input weight row, k odd -> im)
  // layer1 scaled by 1/16 (ortho fwd H-FFT norm folded in).
  f16x8 B1R, B1I, B2R, B2I;
  #pragma unroll
  for (int j=0;j<8;++j){
    const int i = kb*4 + (j>>1);
    const float a1r = w1[(n*16+i)*16+o], a1i = w1[2048 + (n*16+i)*16+o];
    const float a2r = w2[(n*16+i)*16+o], a2i = w2[2048 + (n*16+i)*16+o];
    B1R[j] = (f16)(((j&1) ? -a1i : a1r) * 0.0625f);
    B1I[j] = (f16)(((j&1) ?  a1r : a1i) * 0.0625f);
    B2R[j] = (f16)((j&1) ? -a2i : a2r);
    B2I[j] = (f16)((j&1) ?  a2r : a2i);
  }
  const float b1r = b1[n*16+o],     b1i = b1[128 + n*16+o];
  const float b2r = b2[n*16+o],     b2i = b2[128 + n*16+o];
  const f32x4 cR1 = {b1r,b1r,b1r,b1r}, cI1 = {b1i,b1i,b1i,b1i};
  const f32x4 cR2 = {b2r,b2r,b2r,b2r}, cI2 = {b2i,b2i,b2i,b2i};

  // transpose data columns into xp rows (raw half2 copy; K stays interleaved re/im)
  #pragma unroll
  for (int i=0;i<16;++i) xp[t*17 + i] = data[(i<<8) + t];
  __syncthreads();

  const int* xpI  = (const int*)xp;
  const int* o1bI = (const int*)o1b;
  __half2*  ob    = o1b + wid*(16*17);

  #pragma unroll
  for (int tt=0; tt<4; ++tt){
    const int p0 = wid*64 + tt*16;
    f16x8 A1;
    { int4 tmp;
      const int ab = (p0 + o)*17 + kb*4;
      tmp.x=xpI[ab]; tmp.y=xpI[ab+1]; tmp.z=xpI[ab+2]; tmp.w=xpI[ab+3];
      A1 = __builtin_bit_cast(f16x8, tmp); }
    f32x4 aR = __builtin_amdgcn_mfma_f32_16x16x32_f16(A1, B1R, cR1, 0,0,0);
    f32x4 aI = __builtin_amdgcn_mfma_f32_16x16x32_f16(A1, B1I, cI1, 0,0,0);
    #pragma unroll
    for (int r=0;r<4;++r)
      ob[(kb*4+r)*17 + o] = f2h2(fmaxf(aR[r],0.f), fmaxf(aI[r],0.f));
    f16x8 A2;
    { int4 tmp;
      const int ab = wid*(16*17) + o*17 + kb*4;
      tmp.x=o1bI[ab]; tmp.y=o1bI[ab+1]; tmp.z=o1bI[ab+2]; tmp.w=o1bI[ab+3];
      A2 = __builtin_bit_cast(f16x8, tmp); }
    f32x4 oR = __builtin_amdgcn_mfma_f32_16x16x32_f16(A2, B2R, cR2, 0,0,0);
    f32x4 oI = __builtin_amdgcn_mfma_f32_16x16x32_f16(A2, B2I, cI2, 0,0,0);
    #pragma unroll
    for (int r=0;r<4;++r)
      xp[(p0 + kb*4 + r)*17 + o] = f2h2(sshrink(oR[r]), sshrink(oI[r]));
  }
  __syncthreads();

  // xp rows -> data columns
  #pragma unroll
  for (int i=0;i<16;++i) data[(i<<8) + t] = xp[t*17 + i];
  __syncthreads();

  fft256<1>(data, 16, t, 256);
}

// grid (128, 8, 4): wf<128 from buf2
__global__ __launch_bounds__(256) void k_spec(__half2* __restrict__ buf2,
    const float* __restrict__ w1, const float* __restrict__ b1,
    const float* __restrict__ w2, const float* __restrict__ b2)
{
  __shared__ __half2 data[16*256];
  __shared__ __half2 xp[256*17];
  __shared__ __half2 o1b[4*16*17];
  const int t = threadIdx.x;
  const int wf = blockIdx.x, n = blockIdx.y, b = blockIdx.z;
  __half2* chunk = buf2 + ((size_t)((b*8 + n)*128 + wf) << 12);
  #pragma unroll
  for (int p=0; p<4; ++p) ((float4*)data)[(p<<8)+t] = ((const float4*)chunk)[(p<<8)+t];
  __syncthreads();
  spec_body(data, xp, o1b, n, w1,b1,w2,b2, t);
  #pragma unroll
  for (int p=0; p<4; ++p) ((float4*)chunk)[(p<<8)+t] = ((const float4*)data)[(p<<8)+t];
}

// grid (8, 4): wf==128 (Nyquist) gathered straight from buf1 col 128
__global__ __launch_bounds__(256) void k_spec_nyq(__half2* __restrict__ buf1,
    const float* __restrict__ w1, const float* __restrict__ b1,
    const float* __restrict__ w2, const float* __restrict__ b2)
{
  __shared__ __half2 data[16*256];
  __shared__ __half2 xp[256*17];
  __shared__ __half2 o1b[4*16*17];
  const int t = threadIdx.x;
  const int n = blockIdx.x, b = blockIdx.y;
  #pragma unroll
  for (int i=0;i<16;++i)
    data[(i<<8) + t] = buf1[((size_t)(b*128 + n*16 + i)*256 + t)*WFP + 128];
  __syncthreads();
  spec_body(data, xp, o1b, n, w1,b1,w2,b2, t);
  #pragma unroll
  for (int i=0;i<16;++i)
    buf1[((size_t)(b*128 + n*16 + i)*256 + t)*WFP + 128] = data[(i<<8) + t];
}

// ---------------- T2: [B][n][wf][i][H] -> [B][C][H][132] cols 0..127 ----------------
__global__ __launch_bounds__(256) void k_t2(const __half2* __restrict__ src, __half2* __restrict__ dst)
{
  __shared__ __half2 tile[32][33];
  const int t = threadIdx.x;
  const int wt = blockIdx.x;
  const int ht = blockIdx.y & 7, c = blockIdx.y >> 3, b = blockIdx.z;
  const int h0 = ht<<5, wf0 = wt<<5;
  const int tr = t>>5, tc = t&31;
  const int n = c>>4, ii = c&15;
  const size_t sbase = (size_t)(b*8 + n)*128;
  #pragma unroll
  for (int p=0; p<4; ++p){
    const int wf = wf0 + (p<<3) + tr, hh = h0 + tc;
    tile[(p<<3)+tr][tc] = src[((sbase + wf)*16 + ii)*256 + hh];
  }
  __syncthreads();
  const size_t dbase = (size_t)(b*128 + c)*256;
  #pragma unroll
  for (int p=0; p<4; ++p){
    const int hh = h0 + (p<<3) + tr, wf = wf0 + tc;
    dst[(dbase + hh)*WFP + wf] = tile[tc][(p<<3)+tr];
  }
}

// ---------------- IFFTW: irfft along W + s = h + y/256 -> st f16 ----------------
// grid 1024 = (b<<8)|h
__global__ __launch_bounds__(256, 2) void k_ifftw(const __half2* __restrict__ buf1,
    const f16* __restrict__ h2t, f16* __restrict__ st)
{
  __shared__ __half2 fb[64*256];
  const int t = threadIdx.x;
  const int b = blockIdx.x >> 8, h = blockIdx.x & 255;

  const int k = t;
  const int km = (256 - t) & 255;
  const bool lo = (k <= 128);
  const int kk = lo ? k : km;
  for (int it=0; it<64; ++it){
    const size_t pa = ((size_t)(b*128 + 2*it)*256 + h)*WFP;
    const float2 va = h2f2(buf1[pa + kk]);
    const float2 vb = h2f2(buf1[pa + 256*WFP + kk]);
    float2 Z = lo ? make_float2(va.x - vb.y, va.y + vb.x)
                  : make_float2(va.x + vb.y, vb.x - va.y);
    if (k == 0 || k == 128) Z = make_float2(va.x, vb.x);
    fb[(it<<8) + rev4(k)] = f2h2(Z.x, Z.y);
  }
  __syncthreads();

  fft256<1>(fb, 64, t, 256);   // y (unnormalized: 256x ortho)

  const size_t pg = (size_t)blockIdx.x*256 + t;
  const f16* hrow = h2t + pg*128;
  f16* srow = st + pg*128;
  #pragma unroll
  for (int i=0;i<16;++i){
    const f16x8 hv = ((const f16x8*)hrow)[i];
    f16x8 sv;
    #pragma unroll
    for (int j=0;j<4;++j){
      const float2 y = h2f2(fb[(i*4+j)*256 + t]);
      sv[2*j]   = (f16)((float)hv[2*j]   + y.x*0.00390625f);
      sv[2*j+1] = (f16)((float)hv[2*j+1] + y.y*0.00390625f);
    }
    ((f16x8*)srow)[i] = sv;
  }
}

// ---------------- GEMM2: out = p2 . s + p2b + x, MFMA ----------------
// grid 2048: tile M=128 o x N=128 pixels
__global__ __launch_bounds__(256) void k_gemm2(const f16* __restrict__ st, const float* __restrict__ w,
    const float* __restrict__ bias, const float* __restrict__ xg, float* __restrict__ outg)
{
  __shared__ f16 sa[128][72];
  __shared__ f16 wl[128][72];
  typedef _Float16 f16x2 __attribute__((ext_vector_type(2)));
  const int t = threadIdx.x, l = t&63, wid = t>>6;
  const int col = l&31;
  const size_t pg0 = (size_t)blockIdx.x * 128;
  f32x16 acc0=zero16(), acc1=zero16(), acc2=zero16(), acc3=zero16();
  for (int kk=0; kk<2; ++kk){
    __syncthreads();
    { const int row=t>>1, cb=(t&1)*32;
      const f16x8* src=(const f16x8*)(st + (pg0+row)*128 + kk*64 + cb);
      f16x8* dst=(f16x8*)&sa[row][cb];
      dst[0]=src[0]; dst[1]=src[1]; dst[2]=src[2]; dst[3]=src[3]; }
    { const int row=t>>1, cb=(t&1)*32;
      const float4* src=(const float4*)(w + row*128 + kk*64 + cb);
      #pragma unroll
      for(int i=0;i<8;++i){ const float4 v=src[i];
        f16x2 p0={(f16)v.x,(f16)v.y}, p1={(f16)v.z,(f16)v.w};
        *(f16x2*)&wl[row][cb+4*i]=p0; *(f16x2*)&wl[row][cb+4*i+2]=p1; } }
    __syncthreads();
    #pragma unroll
    for (int c=0;c<4;++c){
      const int ko = c*16 + (l>>5)*8;
      const f16x8 a  = *(const f16x8*)&wl[wid*32+col][ko];
      const f16x8 v0 = *(const f16x8*)&sa[  0+col][ko];
      const f16x8 v1 = *(const f16x8*)&sa[ 32+col][ko];
      const f16x8 v2 = *(const f16x8*)&sa[ 64+col][ko];
      const f16x8 v3 = *(const f16x8*)&sa[ 96+col][ko];
      acc0 = __builtin_amdgcn_mfma_f32_32x32x16_f16(a, v0, acc0, 0,0,0);
      acc1 = __builtin_amdgcn_mfma_f32_32x32x16_f16(a, v1, acc1, 0,0,0);
      acc2 = __builtin_amdgcn_mfma_f32_32x32x16_f16(a, v2, acc2, 0,0,0);
      acc3 = __builtin_amdgcn_mfma_f32_32x32x16_f16(a, v3, acc3, 0,0,0);
    }
  }
  const int b = (int)(pg0>>16), hw0 = (int)(pg0 & 65535);
  const int orow = wid*32 + 4*(l>>5);
  auto store2 = [&](const f32x16& A, int nt){
    #pragma unroll
    for (int r=0;r<16;++r){
      const int o = orow + (r&3) + 8*(r>>2);
      const size_t addr = (((size_t)(b*128+o))<<16) + (size_t)(hw0 + nt*32 + col);
      outg[addr] = A[r] + bias[o] + xg[addr];
    }
  };
  store2(acc0,0); store2(acc1,1); store2(acc2,2); store2(acc3,3);
}

extern "C" void kernel_launch(void* const* d_in, const int* in_sizes, int n_in,
                              void* d_out, int out_size, void* d_ws, size_t ws_size,
                              hipStream_t stream)
{
  (void)in_sizes; (void)n_in; (void)out_size;
  const float* x   = (const float*)d_in[0];
  const float* p1w = (const float*)d_in[1];
  const float* p1b = (const float*)d_in[2];
  const float* w1  = (const float*)d_in[3];
  const float* b1  = (const float*)d_in[4];
  const float* w2  = (const float*)d_in[5];
  const float* b2  = (const float*)d_in[6];
  const float* p2w = (const float*)d_in[7];
  const float* p2b = (const float*)d_in[8];
  float* out = (float*)d_out;

  const size_t BUF1_B = 4UL*128*256*WFP*4;   // 69,206,016  (ws, proven to fit)
  const size_t ST_B   = 262144UL*128*2;      // 67,108,864
  // Placement:
  //   ws   : buf1 [0,69.2M)
  //   d_out: buf2' (wf<128) [0,67.1M)  |  h^T f16 [67.1M,134.2M)  (exact fit)
  //   s^T  : ws tail if it fits, else buf2' region then d2d copy onto dead buf1
  __half2* buf1 = (__half2*)d_ws;
  __half2* buf2 = (__half2*)d_out;
  f16*     h2t  = (f16*)((char*)d_out + ST_B);
  const bool bigws = ws_size >= BUF1_B + ST_B;
  f16* st_w = bigws ? (f16*)((char*)d_ws + BUF1_B) : (f16*)d_out;
  f16* st_r = bigws ? st_w : (f16*)d_ws;

  k_gemm1   <<<dim3(2048),      dim3(256), 0, stream>>>(x, p1w, p1b, h2t);
  k_fftw    <<<dim3(1024),      dim3(256), 0, stream>>>(h2t, buf1);
  k_t1      <<<dim3(4,1024,4),  dim3(256), 0, stream>>>(buf1, buf2);
  k_spec    <<<dim3(128,8,4),   dim3(256), 0, stream>>>(buf2, w1, b1, w2, b2);
  k_spec_nyq<<<dim3(8,4),       dim3(256), 0, stream>>>(buf1, w1, b1, w2, b2);
  k_t2      <<<dim3(4,1024,4),  dim3(256), 0, stream>>>(buf2, buf1);
  k_ifftw   <<<dim3(1024),      dim3(256), 0, stream>>>(buf1, h2t, st_w);
  if (!bigws) (void)hipMemcpyAsync(d_ws, d_out, ST_B, hipMemcpyDeviceToDevice, stream);
  k_gemm2   <<<dim3(2048),      dim3(256), 0, stream>>>(st_r, p2w, p2b, x, out);
}

// Round 6
// 396.363 us; speedup vs baseline: 3.7911x; 1.0391x over previous
//
#include <hip/hip_runtime.h>
#include <hip/hip_fp16.h>

#define DEVI __device__ __forceinline__

// B=4, C=128, H=W=256, Wf=129 (buf1 stride 132), nb=8, bs=16
#define WFP 132

typedef _Float16 f16;
typedef _Float16 f16x8 __attribute__((ext_vector_type(8)));
typedef _Float16 f16x4 __attribute__((ext_vector_type(4)));
typedef float    f32x4  __attribute__((ext_vector_type(4)));
typedef float    f32x16 __attribute__((ext_vector_type(16)));

DEVI float2 cmul(float2 a, float2 b){ return make_float2(fmaf(a.x,b.x,-(a.y*b.y)), fmaf(a.x,b.y,a.y*b.x)); }
DEVI float2 h2f2(__half2 v){ return make_float2(__low2float(v), __high2float(v)); }
DEVI __half2 f2h2(float a, float b){ return __floats2half2_rn(a, b); }
DEVI int rev4(int k){ return ((k&3)<<6) | (((k>>2)&3)<<4) | (((k>>4)&3)<<2) | ((k>>6)&3); }
DEVI float gelu(float v){ return 0.5f*v*(1.0f + erff(v*0.70710678118654752f)); }
DEVI float sshrink(float v){ return v > 0.01f ? v-0.01f : (v < -0.01f ? v+0.01f : 0.0f); }
// LDS bank swizzle (word-granular involution): folds addr[7:5] into addr[2:0].
DEVI int swz(int a){ return a ^ ((a>>5)&7); }
DEVI f32x16 zero16(){
  f32x16 z;
#pragma unroll
  for (int i=0;i<16;++i) z[i]=0.f;
  return z;
}

// In-place FFT over `rows` rows of 256 complex values (half2 in LDS, fp32 math).
// DIR=-1: forward DIF (natural in -> base-4 digit-reversed out).
// DIR=+1: inverse DIT (digit-reversed in -> natural out, UNNORMALIZED).
// SW: apply bank swizzle to all LDS addresses (caller must use the same swizzle).
template<int DIR, bool SW>
DEVI void fft256(__half2* d, int rows, int tid, int nthr){
  const int nbf = rows<<6;
  #pragma unroll
  for (int si=0; si<4; ++si){
    const int lq = (DIR<0) ? (6-2*si) : (2*si);
    const int q4 = 1<<lq;
    const int tws = 64>>lq;
    for (int u = tid; u < nbf; u += nthr){
      const int row = u>>6, w = u&63;
      const int j = w & (q4-1);
      const int blk = w >> lq;
      const int base = (row<<8) + (blk<<(lq+2)) + j;
      const int a0 = SW ? swz(base)        : base;
      const int a1 = SW ? swz(base+q4)     : base+q4;
      const int a2 = SW ? swz(base+2*q4)   : base+2*q4;
      const int a3 = SW ? swz(base+3*q4)   : base+3*q4;
      const int e = j*tws;
      float sn, cs;
      __sincosf((float)(DIR*e) * 0.0245436926061703f, &sn, &cs);
      const float2 w1 = make_float2(cs, sn);
      const float2 w2 = make_float2(cs*cs - sn*sn, 2.f*cs*sn);
      const float2 w3 = cmul(w2, w1);
      if (DIR < 0){
        float2 x0 = h2f2(d[a0]);
        float2 x1 = h2f2(d[a1]);
        float2 x2 = h2f2(d[a2]);
        float2 x3 = h2f2(d[a3]);
        float2 t0 = make_float2(x0.x+x2.x, x0.y+x2.y);
        float2 t1 = make_float2(x0.x-x2.x, x0.y-x2.y);
        float2 t2 = make_float2(x1.x+x3.x, x1.y+x3.y);
        float2 t3 = make_float2(x1.y-x3.y, x3.x-x1.x);
        float2 u1 = cmul(make_float2(t1.x+t3.x, t1.y+t3.y), w1);
        float2 u2 = cmul(make_float2(t0.x-t2.x, t0.y-t2.y), w2);
        float2 u3 = cmul(make_float2(t1.x-t3.x, t1.y-t3.y), w3);
        d[a0] = f2h2(t0.x+t2.x, t0.y+t2.y);
        d[a1] = f2h2(u1.x, u1.y);
        d[a2] = f2h2(u2.x, u2.y);
        d[a3] = f2h2(u3.x, u3.y);
      } else {
        float2 x0  = h2f2(d[a0]);
        float2 b1v = cmul(h2f2(d[a1]), w1);
        float2 b2v = cmul(h2f2(d[a2]), w2);
        float2 b3v = cmul(h2f2(d[a3]), w3);
        float2 t0 = make_float2(x0.x+b2v.x, x0.y+b2v.y);
        float2 t1 = make_float2(x0.x-b2v.x, x0.y-b2v.y);
        float2 t2 = make_float2(b1v.x+b3v.x, b1v.y+b3v.y);
        float2 t3 = make_float2(-(b1v.y-b3v.y), b1v.x-b3v.x);
        d[a0] = f2h2(t0.x+t2.x, t0.y+t2.y);
        d[a1] = f2h2(t1.x+t3.x, t1.y+t3.y);
        d[a2] = f2h2(t0.x-t2.x, t0.y-t2.y);
        d[a3] = f2h2(t1.x-t3.x, t1.y-t3.y);
      }
    }
    __syncthreads();
  }
}

// ---------------- GEMM1 (fused transpose): h^T[pg][co] = gelu(p1w.x + p1b) ----------------
// grid 2048: tile M=128 pixels x N=128 co, K=128 in 2 halves. 4 waves.
__global__ __launch_bounds__(256) void k_gemm1(const float* __restrict__ xg, const float* __restrict__ w,
    const float* __restrict__ bias, f16* __restrict__ h2t)
{
  __shared__ f16 wl[128][136];
  __shared__ f16 xa[128][72];
  const int t = threadIdx.x, l = t&63, wid = t>>6;
  const size_t pg0 = (size_t)blockIdx.x * 128;
  const int b = (int)(pg0>>16), hw0 = (int)(pg0&65535);

  #pragma unroll
  for (int i=0;i<16;++i){
    const int f4 = i*256 + t;
    const int row = f4>>5, col = (f4&31)*4;
    const float4 v = ((const float4*)w)[f4];
    const f16x4 pk = {(f16)v.x,(f16)v.y,(f16)v.z,(f16)v.w};
    *(f16x4*)&wl[row][col] = pk;
  }

  f32x16 acc[4];
  #pragma unroll
  for (int nt=0;nt<4;++nt) acc[nt]=zero16();

  const int px = t&127, cq = t>>7;
  for (int kk=0; kk<2; ++kk){
    __syncthreads();
    #pragma unroll
    for (int i=0;i<8;++i){
      const int c4 = (cq + 2*i)*4;
      const float* xp = xg + (((size_t)(b*128 + kk*64 + c4))<<16) + hw0 + px;
      const float v0 = xp[0];
      const float v1 = xp[65536];
      const float v2 = xp[131072];
      const float v3 = xp[196608];
      const f16x4 pk = {(f16)v0,(f16)v1,(f16)v2,(f16)v3};
      *(f16x4*)&xa[px][c4] = pk;
    }
    __syncthreads();
    #pragma unroll
    for (int kq=0; kq<4; ++kq){
      const f16x8 A = *(const f16x8*)&xa[wid*32 + (l&31)][kq*16 + (l>>5)*8];
      #pragma unroll
      for (int nt=0; nt<4; ++nt){
        const f16x8 Bf = *(const f16x8*)&wl[nt*32 + (l&31)][kk*64 + kq*16 + (l>>5)*8];
        acc[nt] = __builtin_amdgcn_mfma_f32_32x32x16_f16(A, Bf, acc[nt], 0,0,0);
      }
    }
  }
  #pragma unroll
  for (int nt=0;nt<4;++nt){
    const int co = nt*32 + (l&31);
    const float bi = bias[co];
    #pragma unroll
    for (int r=0;r<16;++r){
      const int p = wid*32 + (r&3) + 8*(r>>2) + 4*(l>>5);
      h2t[(pg0+(size_t)p)*128 + co] = (f16)gelu(acc[nt][r] + bi);
    }
  }
}

// ---------------- FFTW: rfft along W of h rows -> buf1 ----------------
// grid 2048 = (bh<<1)|half; 32 packed rows (64 channels) per block; 32KB LDS; swizzled
__global__ __launch_bounds__(256) void k_fftw(const f16* __restrict__ h2t, __half2* __restrict__ buf1)
{
  __shared__ __half2 fb[32*256];
  const int t = threadIdx.x;
  const int bh = blockIdx.x >> 1, half = blockIdx.x & 1;
  const int b = bh >> 8, h = bh & 255;
  const size_t pg = (size_t)bh*256 + t;
  const f16* row = h2t + pg*128 + half*64;
  #pragma unroll
  for (int i=0;i<8;++i){
    const f16x8 v = ((const f16x8*)row)[i];
    const __half2* vp = (const __half2*)&v;
    #pragma unroll
    for (int j=0;j<4;++j) fb[swz((i*4+j)*256 + t)] = vp[j];
  }
  __syncthreads();

  fft256<-1,true>(fb, 32, t, 256);

  #pragma unroll
  for (int it=0; it<16; ++it){
    const int idx = (it<<8) + t;
    const int r = idx>>7, k = idx&127;        // r 0..31
    const float2 zk = h2f2(fb[swz((r<<8) + rev4(k))]);
    const float2 zm = h2f2(fb[swz((r<<8) + rev4((256-k)&255))]);
    const float ar = (zk.x+zm.x)*0.03125f, ai = (zk.y-zm.y)*0.03125f;
    const float br = (zk.y+zm.y)*0.03125f, bi = (zm.x-zk.x)*0.03125f;
    const int ch = half*64 + 2*r;
    const size_t pa = ((size_t)(b*128 + ch)*256 + h)*WFP + k;
    buf1[pa]           = f2h2(ar, ai);
    buf1[pa + 256*WFP] = f2h2(br, bi);
  }
  if (t < 32){   // Nyquist k=128
    const int r = t;
    const float2 zk = h2f2(fb[swz((r<<8) + rev4(128))]);
    const int ch = half*64 + 2*r;
    const size_t pa = ((size_t)(b*128 + ch)*256 + h)*WFP + 128;
    buf1[pa]           = f2h2(zk.x*0.0625f, 0.f);
    buf1[pa + 256*WFP] = f2h2(zk.y*0.0625f, 0.f);
  }
}

// ---------------- T1: [B][C][H][132] cols 0..127 -> [B][n][wf][i][H] ----------------
// grid (4, 1024, 4)
__global__ __launch_bounds__(256) void k_t1(const __half2* __restrict__ src, __half2* __restrict__ dst)
{
  __shared__ __half2 tile[32][33];
  const int t = threadIdx.x;
  const int wt = blockIdx.x;
  const int ht = blockIdx.y & 7, c = blockIdx.y >> 3, b = blockIdx.z;
  const int h0 = ht<<5, wf0 = wt<<5;
  const int tr = t>>5, tc = t&31;
  const size_t sbase = (size_t)(b*128 + c)*256;
  #pragma unroll
  for (int p=0; p<4; ++p){
    const int hh = h0 + (p<<3) + tr, wf = wf0 + tc;
    tile[(p<<3)+tr][tc] = src[(sbase + hh)*WFP + wf];
  }
  __syncthreads();
  const int n = c>>4, ii = c&15;
  const size_t dbase = (size_t)(b*8 + n)*128;
  #pragma unroll
  for (int p=0; p<4; ++p){
    const int wf = wf0 + (p<<3) + tr, hh = h0 + tc;
    dst[((dbase + wf)*16 + ii)*256 + hh] = tile[tc][(p<<3)+tr];
  }
}

// ---------------- spec body v2: FFT along H + complex block-MLP (MFMA) + inverse ----------------
DEVI void spec_body(__half2* data, __half2* xp, __half2* o1b, int n,
                    const float* __restrict__ w1, const float* __restrict__ b1,
                    const float* __restrict__ w2, const float* __restrict__ b2, int t)
{
  fft256<-1,false>(data, 16, t, 256);

  const int l = t&63, wid = t>>6;
  const int o = l&15, kb = l>>4;

  f16x8 B1R, B1I, B2R, B2I;
  #pragma unroll
  for (int j=0;j<8;++j){
    const int i = kb*4 + (j>>1);
    const float a1r = w1[(n*16+i)*16+o], a1i = w1[2048 + (n*16+i)*16+o];
    const float a2r = w2[(n*16+i)*16+o], a2i = w2[2048 + (n*16+i)*16+o];
    B1R[j] = (f16)(((j&1) ? -a1i : a1r) * 0.0625f);
    B1I[j] = (f16)(((j&1) ?  a1r : a1i) * 0.0625f);
    B2R[j] = (f16)((j&1) ? -a2i : a2r);
    B2I[j] = (f16)((j&1) ?  a2r : a2i);
  }
  const float b1r = b1[n*16+o],     b1i = b1[128 + n*16+o];
  const float b2r = b2[n*16+o],     b2i = b2[128 + n*16+o];
  const f32x4 cR1 = {b1r,b1r,b1r,b1r}, cI1 = {b1i,b1i,b1i,b1i};
  const f32x4 cR2 = {b2r,b2r,b2r,b2r}, cI2 = {b2i,b2i,b2i,b2i};

  #pragma unroll
  for (int i=0;i<16;++i) xp[t*17 + i] = data[(i<<8) + t];
  __syncthreads();

  const int* xpI  = (const int*)xp;
  const int* o1bI = (const int*)o1b;
  __half2*  ob    = o1b + wid*(16*17);

  #pragma unroll
  for (int tt=0; tt<4; ++tt){
    const int p0 = wid*64 + tt*16;
    f16x8 A1;
    { int4 tmp;
      const int ab = (p0 + o)*17 + kb*4;
      tmp.x=xpI[ab]; tmp.y=xpI[ab+1]; tmp.z=xpI[ab+2]; tmp.w=xpI[ab+3];
      A1 = __builtin_bit_cast(f16x8, tmp); }
    f32x4 aR = __builtin_amdgcn_mfma_f32_16x16x32_f16(A1, B1R, cR1, 0,0,0);
    f32x4 aI = __builtin_amdgcn_mfma_f32_16x16x32_f16(A1, B1I, cI1, 0,0,0);
    #pragma unroll
    for (int r=0;r<4;++r)
      ob[(kb*4+r)*17 + o] = f2h2(fmaxf(aR[r],0.f), fmaxf(aI[r],0.f));
    f16x8 A2;
    { int4 tmp;
      const int ab = wid*(16*17) + o*17 + kb*4;
      tmp.x=o1bI[ab]; tmp.y=o1bI[ab+1]; tmp.z=o1bI[ab+2]; tmp.w=o1bI[ab+3];
      A2 = __builtin_bit_cast(f16x8, tmp); }
    f32x4 oR = __builtin_amdgcn_mfma_f32_16x16x32_f16(A2, B2R, cR2, 0,0,0);
    f32x4 oI = __builtin_amdgcn_mfma_f32_16x16x32_f16(A2, B2I, cI2, 0,0,0);
    #pragma unroll
    for (int r=0;r<4;++r)
      xp[(p0 + kb*4 + r)*17 + o] = f2h2(sshrink(oR[r]), sshrink(oI[r]));
  }
  __syncthreads();

  #pragma unroll
  for (int i=0;i<16;++i) data[(i<<8) + t] = xp[t*17 + i];
  __syncthreads();

  fft256<1,false>(data, 16, t, 256);
}

// grid (128, 8, 4): wf<128 from buf2
__global__ __launch_bounds__(256) void k_spec(__half2* __restrict__ buf2,
    const float* __restrict__ w1, const float* __restrict__ b1,
    const float* __restrict__ w2, const float* __restrict__ b2)
{
  __shared__ __half2 data[16*256];
  __shared__ __half2 xp[256*17];
  __shared__ __half2 o1b[4*16*17];
  const int t = threadIdx.x;
  const int wf = blockIdx.x, n = blockIdx.y, b = blockIdx.z;
  __half2* chunk = buf2 + ((size_t)((b*8 + n)*128 + wf) << 12);
  #pragma unroll
  for (int p=0; p<4; ++p) ((float4*)data)[(p<<8)+t] = ((const float4*)chunk)[(p<<8)+t];
  __syncthreads();
  spec_body(data, xp, o1b, n, w1,b1,w2,b2, t);
  #pragma unroll
  for (int p=0; p<4; ++p) ((float4*)chunk)[(p<<8)+t] = ((const float4*)data)[(p<<8)+t];
}

// grid (8, 4): wf==128 (Nyquist) gathered straight from buf1 col 128
__global__ __launch_bounds__(256) void k_spec_nyq(__half2* __restrict__ buf1,
    const float* __restrict__ w1, const float* __restrict__ b1,
    const float* __restrict__ w2, const float* __restrict__ b2)
{
  __shared__ __half2 data[16*256];
  __shared__ __half2 xp[256*17];
  __shared__ __half2 o1b[4*16*17];
  const int t = threadIdx.x;
  const int n = blockIdx.x, b = blockIdx.y;
  #pragma unroll
  for (int i=0;i<16;++i)
    data[(i<<8) + t] = buf1[((size_t)(b*128 + n*16 + i)*256 + t)*WFP + 128];
  __syncthreads();
  spec_body(data, xp, o1b, n, w1,b1,w2,b2, t);
  #pragma unroll
  for (int i=0;i<16;++i)
    buf1[((size_t)(b*128 + n*16 + i)*256 + t)*WFP + 128] = data[(i<<8) + t];
}

// ---------------- T2: [B][n][wf][i][H] -> [B][C][H][132] cols 0..127 ----------------
__global__ __launch_bounds__(256) void k_t2(const __half2* __restrict__ src, __half2* __restrict__ dst)
{
  __shared__ __half2 tile[32][33];
  const int t = threadIdx.x;
  const int wt = blockIdx.x;
  const int ht = blockIdx.y & 7, c = blockIdx.y >> 3, b = blockIdx.z;
  const int h0 = ht<<5, wf0 = wt<<5;
  const int tr = t>>5, tc = t&31;
  const int n = c>>4, ii = c&15;
  const size_t sbase = (size_t)(b*8 + n)*128;
  #pragma unroll
  for (int p=0; p<4; ++p){
    const int wf = wf0 + (p<<3) + tr, hh = h0 + tc;
    tile[(p<<3)+tr][tc] = src[((sbase + wf)*16 + ii)*256 + hh];
  }
  __syncthreads();
  const size_t dbase = (size_t)(b*128 + c)*256;
  #pragma unroll
  for (int p=0; p<4; ++p){
    const int hh = h0 + (p<<3) + tr, wf = wf0 + tc;
    dst[(dbase + hh)*WFP + wf] = tile[tc][(p<<3)+tr];
  }
}

// ---------------- IFFTW: irfft along W + s = h + y/256 -> st f16 ----------------
// grid 2048 = (bh<<1)|half; 32 packed rows per block; 32KB LDS; swizzled
__global__ __launch_bounds__(256) void k_ifftw(const __half2* __restrict__ buf1,
    const f16* __restrict__ h2t, f16* __restrict__ st)
{
  __shared__ __half2 fb[32*256];
  const int t = threadIdx.x;
  const int bh = blockIdx.x >> 1, half = blockIdx.x & 1;
  const int b = bh >> 8, h = bh & 255;

  const int k = t;
  const int km = (256 - t) & 255;
  const bool lo = (k <= 128);
  const int kk = lo ? k : km;
  #pragma unroll
  for (int it=0; it<32; ++it){
    const int ch = half*64 + 2*it;
    const size_t pa = ((size_t)(b*128 + ch)*256 + h)*WFP;
    const float2 va = h2f2(buf1[pa + kk]);
    const float2 vb = h2f2(buf1[pa + 256*WFP + kk]);
    float2 Z = lo ? make_float2(va.x - vb.y, va.y + vb.x)
                  : make_float2(va.x + vb.y, vb.x - va.y);
    if (k == 0 || k == 128) Z = make_float2(va.x, vb.x);
    fb[swz((it<<8) + rev4(k))] = f2h2(Z.x, Z.y);
  }
  __syncthreads();

  fft256<1,true>(fb, 32, t, 256);   // y (unnormalized: 256x ortho)

  const size_t pg = (size_t)bh*256 + t;
  const f16* hrow = h2t + pg*128 + half*64;
  f16* srow = st + pg*128 + half*64;
  #pragma unroll
  for (int i=0;i<8;++i){
    const f16x8 hv = ((const f16x8*)hrow)[i];
    f16x8 sv;
    #pragma unroll
    for (int j=0;j<4;++j){
      const float2 y = h2f2(fb[swz((i*4+j)*256 + t)]);
      sv[2*j]   = (f16)((float)hv[2*j]   + y.x*0.00390625f);
      sv[2*j+1] = (f16)((float)hv[2*j+1] + y.y*0.00390625f);
    }
    ((f16x8*)srow)[i] = sv;
  }
}

// ---------------- GEMM2: out = p2 . s + p2b + x, MFMA ----------------
// grid 2048: tile M=128 o x N=128 pixels
__global__ __launch_bounds__(256) void k_gemm2(const f16* __restrict__ st, const float* __restrict__ w,
    const float* __restrict__ bias, const float* __restrict__ xg, float* __restrict__ outg)
{
  __shared__ f16 sa[128][72];
  __shared__ f16 wl[128][72];
  typedef _Float16 f16x2 __attribute__((ext_vector_type(2)));
  const int t = threadIdx.x, l = t&63, wid = t>>6;
  const int col = l&31;
  const size_t pg0 = (size_t)blockIdx.x * 128;
  f32x16 acc0=zero16(), acc1=zero16(), acc2=zero16(), acc3=zero16();
  for (int kk=0; kk<2; ++kk){
    __syncthreads();
    { const int row=t>>1, cb=(t&1)*32;
      const f16x8* src=(const f16x8*)(st + (pg0+row)*128 + kk*64 + cb);
      f16x8* dst=(f16x8*)&sa[row][cb];
      dst[0]=src[0]; dst[1]=src[1]; dst[2]=src[2]; dst[3]=src[3]; }
    { const int row=t>>1, cb=(t&1)*32;
      const float4* src=(const float4*)(w + row*128 + kk*64 + cb);
      #pragma unroll
      for(int i=0;i<8;++i){ const float4 v=src[i];
        f16x2 p0={(f16)v.x,(f16)v.y}, p1={(f16)v.z,(f16)v.w};
        *(f16x2*)&wl[row][cb+4*i]=p0; *(f16x2*)&wl[row][cb+4*i+2]=p1; } }
    __syncthreads();
    #pragma unroll
    for (int c=0;c<4;++c){
      const int ko = c*16 + (l>>5)*8;
      const f16x8 a  = *(const f16x8*)&wl[wid*32+col][ko];
      const f16x8 v0 = *(const f16x8*)&sa[  0+col][ko];
      const f16x8 v1 = *(const f16x8*)&sa[ 32+col][ko];
      const f16x8 v2 = *(const f16x8*)&sa[ 64+col][ko];
      const f16x8 v3 = *(const f16x8*)&sa[ 96+col][ko];
      acc0 = __builtin_amdgcn_mfma_f32_32x32x16_f16(a, v0, acc0, 0,0,0);
      acc1 = __builtin_amdgcn_mfma_f32_32x32x16_f16(a, v1, acc1, 0,0,0);
      acc2 = __builtin_amdgcn_mfma_f32_32x32x16_f16(a, v2, acc2, 0,0,0);
      acc3 = __builtin_amdgcn_mfma_f32_32x32x16_f16(a, v3, acc3, 0,0,0);
    }
  }
  const int b = (int)(pg0>>16), hw0 = (int)(pg0 & 65535);
  const int orow = wid*32 + 4*(l>>5);
  auto store2 = [&](const f32x16& A, int nt){
    #pragma unroll
    for (int r=0;r<16;++r){
      const int o = orow + (r&3) + 8*(r>>2);
      const size_t addr = (((size_t)(b*128+o))<<16) + (size_t)(hw0 + nt*32 + col);
      outg[addr] = A[r] + bias[o] + xg[addr];
    }
  };
  store2(acc0,0); store2(acc1,1); store2(acc2,2); store2(acc3,3);
}

extern "C" void kernel_launch(void* const* d_in, const int* in_sizes, int n_in,
                              void* d_out, int out_size, void* d_ws, size_t ws_size,
                              hipStream_t stream)
{
  (void)in_sizes; (void)n_in; (void)out_size;
  const float* x   = (const float*)d_in[0];
  const float* p1w = (const float*)d_in[1];
  const float* p1b = (const float*)d_in[2];
  const float* w1  = (const float*)d_in[3];
  const float* b1  = (const float*)d_in[4];
  const float* w2  = (const float*)d_in[5];
  const float* b2  = (const float*)d_in[6];
  const float* p2w = (const float*)d_in[7];
  const float* p2b = (const float*)d_in[8];
  float* out = (float*)d_out;

  const size_t BUF1_B = 4UL*128*256*WFP*4;   // 69,206,016  (ws, proven to fit)
  const size_t ST_B   = 262144UL*128*2;      // 67,108,864
  __half2* buf1 = (__half2*)d_ws;
  __half2* buf2 = (__half2*)d_out;
  f16*     h2t  = (f16*)((char*)d_out + ST_B);
  const bool bigws = ws_size >= BUF1_B + ST_B;
  f16* st_w = bigws ? (f16*)((char*)d_ws + BUF1_B) : (f16*)d_out;
  f16* st_r = bigws ? st_w : (f16*)d_ws;

  k_gemm1   <<<dim3(2048),      dim3(256), 0, stream>>>(x, p1w, p1b, h2t);
  k_fftw    <<<dim3(2048),      dim3(256), 0, stream>>>(h2t, buf1);
  k_t1      <<<dim3(4,1024,4),  dim3(256), 0, stream>>>(buf1, buf2);
  k_spec    <<<dim3(128,8,4),   dim3(256), 0, stream>>>(buf2, w1, b1, w2, b2);
  k_spec_nyq<<<dim3(8,4),       dim3(256), 0, stream>>>(buf1, w1, b1, w2, b2);
  k_t2      <<<dim3(4,1024,4),  dim3(256), 0, stream>>>(buf2, buf1);
  k_ifftw   <<<dim3(2048),      dim3(256), 0, stream>>>(buf1, h2t, st_w);
  if (!bigws) (void)hipMemcpyAsync(d_ws, d_out, ST_B, hipMemcpyDeviceToDevice, stream);
  k_gemm2   <<<dim3(2048),      dim3(256), 0, stream>>>(st_r, p2w, p2b, x, out);
}

// Round 7
// 385.305 us; speedup vs baseline: 3.8999x; 1.0287x over previous
//
#include <hip/hip_runtime.h>
#include <hip/hip_fp16.h>

#define DEVI __device__ __forceinline__

// B=4, C=128, H=W=256, Wf=129 (buf1 stride 132), nb=8, bs=16
#define WFP 132

typedef _Float16 f16;
typedef _Float16 f16x8 __attribute__((ext_vector_type(8)));
typedef _Float16 f16x4 __attribute__((ext_vector_type(4)));
typedef float    f32x4  __attribute__((ext_vector_type(4)));
typedef float    f32x16 __attribute__((ext_vector_type(16)));

DEVI float2 cmul(float2 a, float2 b){ return make_float2(fmaf(a.x,b.x,-(a.y*b.y)), fmaf(a.x,b.y,a.y*b.x)); }
DEVI float2 h2f2(__half2 v){ return make_float2(__low2float(v), __high2float(v)); }
DEVI __half2 f2h2(float a, float b){ return __floats2half2_rn(a, b); }
DEVI int rev4(int k){ return ((k&3)<<6) | (((k>>2)&3)<<4) | (((k>>4)&3)<<2) | ((k>>6)&3); }
DEVI float gelu(float v){ return 0.5f*v*(1.0f + erff(v*0.70710678118654752f)); }
DEVI float sshrink(float v){ return v > 0.01f ? v-0.01f : (v < -0.01f ? v+0.01f : 0.0f); }
// LDS bank swizzle (word-granular involution): folds addr[7:5] into addr[2:0].
DEVI int swz(int a){ return a ^ ((a>>5)&7); }
DEVI f32x16 zero16(){
  f32x16 z;
#pragma unroll
  for (int i=0;i<16;++i) z[i]=0.f;
  return z;
}

// In-place FFT over `rows` rows of 256 complex values (half2 in LDS, fp32 math).
// DIR=-1: forward DIF (natural in -> base-4 digit-reversed out).
// DIR=+1: inverse DIT (digit-reversed in -> natural out, UNNORMALIZED).
// SW: apply bank swizzle to all LDS addresses (caller must use the same swizzle).
template<int DIR, bool SW>
DEVI void fft256(__half2* d, int rows, int tid, int nthr){
  const int nbf = rows<<6;
  #pragma unroll
  for (int si=0; si<4; ++si){
    const int lq = (DIR<0) ? (6-2*si) : (2*si);
    const int q4 = 1<<lq;
    const int tws = 64>>lq;
    for (int u = tid; u < nbf; u += nthr){
      const int row = u>>6, w = u&63;
      const int j = w & (q4-1);
      const int blk = w >> lq;
      const int base = (row<<8) + (blk<<(lq+2)) + j;
      const int a0 = SW ? swz(base)        : base;
      const int a1 = SW ? swz(base+q4)     : base+q4;
      const int a2 = SW ? swz(base+2*q4)   : base+2*q4;
      const int a3 = SW ? swz(base+3*q4)   : base+3*q4;
      const int e = j*tws;
      float sn, cs;
      __sincosf((float)(DIR*e) * 0.0245436926061703f, &sn, &cs);
      const float2 w1 = make_float2(cs, sn);
      const float2 w2 = make_float2(cs*cs - sn*sn, 2.f*cs*sn);
      const float2 w3 = cmul(w2, w1);
      if (DIR < 0){
        float2 x0 = h2f2(d[a0]);
        float2 x1 = h2f2(d[a1]);
        float2 x2 = h2f2(d[a2]);
        float2 x3 = h2f2(d[a3]);
        float2 t0 = make_float2(x0.x+x2.x, x0.y+x2.y);
        float2 t1 = make_float2(x0.x-x2.x, x0.y-x2.y);
        float2 t2 = make_float2(x1.x+x3.x, x1.y+x3.y);
        float2 t3 = make_float2(x1.y-x3.y, x3.x-x1.x);
        float2 u1 = cmul(make_float2(t1.x+t3.x, t1.y+t3.y), w1);
        float2 u2 = cmul(make_float2(t0.x-t2.x, t0.y-t2.y), w2);
        float2 u3 = cmul(make_float2(t1.x-t3.x, t1.y-t3.y), w3);
        d[a0] = f2h2(t0.x+t2.x, t0.y+t2.y);
        d[a1] = f2h2(u1.x, u1.y);
        d[a2] = f2h2(u2.x, u2.y);
        d[a3] = f2h2(u3.x, u3.y);
      } else {
        float2 x0  = h2f2(d[a0]);
        float2 b1v = cmul(h2f2(d[a1]), w1);
        float2 b2v = cmul(h2f2(d[a2]), w2);
        float2 b3v = cmul(h2f2(d[a3]), w3);
        float2 t0 = make_float2(x0.x+b2v.x, x0.y+b2v.y);
        float2 t1 = make_float2(x0.x-b2v.x, x0.y-b2v.y);
        float2 t2 = make_float2(b1v.x+b3v.x, b1v.y+b3v.y);
        float2 t3 = make_float2(-(b1v.y-b3v.y), b1v.x-b3v.x);
        d[a0] = f2h2(t0.x+t2.x, t0.y+t2.y);
        d[a1] = f2h2(t1.x+t3.x, t1.y+t3.y);
        d[a2] = f2h2(t0.x-t2.x, t0.y-t2.y);
        d[a3] = f2h2(t1.x-t3.x, t1.y-t3.y);
      }
    }
    __syncthreads();
  }
}

// ---------------- GEMM1 (fused transpose via global_load_lds): h^T[pg][co] = gelu(p1w.x + p1b) ----------------
// grid 2048: tile M=128 pixels x N=128 co, K=128 in 4 steps of 32. 4 waves.
// xa32: [c][px] f32 staged by global_load_lds (async, linear); A-fragments read as 8
// strided b32 (conflict-free: lanes -> consecutive px) + in-reg cvt. wl: f16 [128][132].
__global__ __launch_bounds__(256) void k_gemm1(const float* __restrict__ xg, const float* __restrict__ w,
    const float* __restrict__ bias, f16* __restrict__ h2t)
{
  __shared__ f16 wl[128][132];     // 33792 B
  __shared__ float xa32[32][128];  // 16384 B  -> total 50176 B: 3 blocks/CU
  const int t = threadIdx.x, l = t&63, wid = t>>6;
  const size_t pg0 = (size_t)blockIdx.x * 128;
  const int b = (int)(pg0>>16), hw0 = (int)(pg0&65535);

  // ---- stage w (16384 f32) once: flat-coalesced float4, f16x4 b64 writes ----
  #pragma unroll
  for (int i=0;i<16;++i){
    const int f4 = i*256 + t;
    const int row = f4>>5, col = (f4&31)*4;
    const float4 v = ((const float4*)w)[f4];
    const f16x4 pk = {(f16)v.x,(f16)v.y,(f16)v.z,(f16)v.w};
    *(f16x4*)&wl[row][col] = pk;
  }

  f32x16 acc[4];
  #pragma unroll
  for (int nt=0;nt<4;++nt) acc[nt]=zero16();

  const int px = wid*32 + (l&31);
  for (int cs=0; cs<4; ++cs){
    __syncthreads();   // xa32 free (prev MFMA done); also covers wl on cs=0
    // ---- stage 32 c-rows of x via global_load_lds (16B/lane, 1KB=2 rows per inst) ----
    {
      const int c_local = wid*8 + (l>>5);          // this inst's base rows: wid*8+ch*2
      #pragma unroll
      for (int ch=0; ch<4; ++ch){
        const float* src = xg + (((size_t)(b*128 + cs*32 + c_local + ch*2))<<16)
                              + hw0 + (l&31)*4;
        __builtin_amdgcn_global_load_lds(src, &xa32[wid*8 + ch*2][0], 16, 0, 0);
      }
    }
    __syncthreads();   // loads landed
    #pragma unroll
    for (int kq=0; kq<2; ++kq){
      const int k0 = kq*16 + (l>>5)*8;
      f16x8 A;
      #pragma unroll
      for (int j=0;j<8;++j) A[j] = (f16)xa32[k0 + j][px];
      #pragma unroll
      for (int nt=0; nt<4; ++nt){
        const f16x8 Bf = *(const f16x8*)&wl[nt*32 + (l&31)][cs*32 + k0];
        acc[nt] = __builtin_amdgcn_mfma_f32_32x32x16_f16(A, Bf, acc[nt], 0,0,0);
      }
    }
  }
  #pragma unroll
  for (int nt=0;nt<4;++nt){
    const int co = nt*32 + (l&31);
    const float bi = bias[co];
    #pragma unroll
    for (int r=0;r<16;++r){
      const int p = wid*32 + (r&3) + 8*(r>>2) + 4*(l>>5);
      h2t[(pg0+(size_t)p)*128 + co] = (f16)gelu(acc[nt][r] + bi);
    }
  }
}

// ---------------- FFTW: rfft along W of h rows -> buf1 ----------------
// grid 2048 = (bh<<1)|half; 32 packed rows (64 channels) per block; 32KB LDS; swizzled
__global__ __launch_bounds__(256) void k_fftw(const f16* __restrict__ h2t, __half2* __restrict__ buf1)
{
  __shared__ __half2 fb[32*256];
  const int t = threadIdx.x;
  const int bh = blockIdx.x >> 1, half = blockIdx.x & 1;
  const int b = bh >> 8, h = bh & 255;
  const size_t pg = (size_t)bh*256 + t;
  const f16* row = h2t + pg*128 + half*64;
  #pragma unroll
  for (int i=0;i<8;++i){
    const f16x8 v = ((const f16x8*)row)[i];
    const __half2* vp = (const __half2*)&v;
    #pragma unroll
    for (int j=0;j<4;++j) fb[swz((i*4+j)*256 + t)] = vp[j];
  }
  __syncthreads();

  fft256<-1,true>(fb, 32, t, 256);

  #pragma unroll
  for (int it=0; it<16; ++it){
    const int idx = (it<<8) + t;
    const int r = idx>>7, k = idx&127;        // r 0..31
    const float2 zk = h2f2(fb[swz((r<<8) + rev4(k))]);
    const float2 zm = h2f2(fb[swz((r<<8) + rev4((256-k)&255))]);
    const float ar = (zk.x+zm.x)*0.03125f, ai = (zk.y-zm.y)*0.03125f;
    const float br = (zk.y+zm.y)*0.03125f, bi = (zm.x-zk.x)*0.03125f;
    const int ch = half*64 + 2*r;
    const size_t pa = ((size_t)(b*128 + ch)*256 + h)*WFP + k;
    buf1[pa]           = f2h2(ar, ai);
    buf1[pa + 256*WFP] = f2h2(br, bi);
  }
  if (t < 32){   // Nyquist k=128
    const int r = t;
    const float2 zk = h2f2(fb[swz((r<<8) + rev4(128))]);
    const int ch = half*64 + 2*r;
    const size_t pa = ((size_t)(b*128 + ch)*256 + h)*WFP + 128;
    buf1[pa]           = f2h2(zk.x*0.0625f, 0.f);
    buf1[pa + 256*WFP] = f2h2(zk.y*0.0625f, 0.f);
  }
}

// ---------------- T1: [B][C][H][132] cols 0..127 -> [B][n][wf][i][H] ----------------
// grid (4, 1024, 4)
__global__ __launch_bounds__(256) void k_t1(const __half2* __restrict__ src, __half2* __restrict__ dst)
{
  __shared__ __half2 tile[32][33];
  const int t = threadIdx.x;
  const int wt = blockIdx.x;
  const int ht = blockIdx.y & 7, c = blockIdx.y >> 3, b = blockIdx.z;
  const int h0 = ht<<5, wf0 = wt<<5;
  const int tr = t>>5, tc = t&31;
  const size_t sbase = (size_t)(b*128 + c)*256;
  #pragma unroll
  for (int p=0; p<4; ++p){
    const int hh = h0 + (p<<3) + tr, wf = wf0 + tc;
    tile[(p<<3)+tr][tc] = src[(sbase + hh)*WFP + wf];
  }
  __syncthreads();
  const int n = c>>4, ii = c&15;
  const size_t dbase = (size_t)(b*8 + n)*128;
  #pragma unroll
  for (int p=0; p<4; ++p){
    const int wf = wf0 + (p<<3) + tr, hh = h0 + tc;
    dst[((dbase + wf)*16 + ii)*256 + hh] = tile[tc][(p<<3)+tr];
  }
}

// ---------------- spec body v2: FFT along H + complex block-MLP (MFMA) + inverse ----------------
DEVI void spec_body(__half2* data, __half2* xp, __half2* o1b, int n,
                    const float* __restrict__ w1, const float* __restrict__ b1,
                    const float* __restrict__ w2, const float* __restrict__ b2, int t)
{
  fft256<-1,false>(data, 16, t, 256);

  const int l = t&63, wid = t>>6;
  const int o = l&15, kb = l>>4;

  f16x8 B1R, B1I, B2R, B2I;
  #pragma unroll
  for (int j=0;j<8;++j){
    const int i = kb*4 + (j>>1);
    const float a1r = w1[(n*16+i)*16+o], a1i = w1[2048 + (n*16+i)*16+o];
    const float a2r = w2[(n*16+i)*16+o], a2i = w2[2048 + (n*16+i)*16+o];
    B1R[j] = (f16)(((j&1) ? -a1i : a1r) * 0.0625f);
    B1I[j] = (f16)(((j&1) ?  a1r : a1i) * 0.0625f);
    B2R[j] = (f16)((j&1) ? -a2i : a2r);
    B2I[j] = (f16)((j&1) ?  a2r : a2i);
  }
  const float b1r = b1[n*16+o],     b1i = b1[128 + n*16+o];
  const float b2r = b2[n*16+o],     b2i = b2[128 + n*16+o];
  const f32x4 cR1 = {b1r,b1r,b1r,b1r}, cI1 = {b1i,b1i,b1i,b1i};
  const f32x4 cR2 = {b2r,b2r,b2r,b2r}, cI2 = {b2i,b2i,b2i,b2i};

  #pragma unroll
  for (int i=0;i<16;++i) xp[t*17 + i] = data[(i<<8) + t];
  __syncthreads();

  const int* xpI  = (const int*)xp;
  const int* o1bI = (const int*)o1b;
  __half2*  ob    = o1b + wid*(16*17);

  #pragma unroll
  for (int tt=0; tt<4; ++tt){
    const int p0 = wid*64 + tt*16;
    f16x8 A1;
    { int4 tmp;
      const int ab = (p0 + o)*17 + kb*4;
      tmp.x=xpI[ab]; tmp.y=xpI[ab+1]; tmp.z=xpI[ab+2]; tmp.w=xpI[ab+3];
      A1 = __builtin_bit_cast(f16x8, tmp); }
    f32x4 aR = __builtin_amdgcn_mfma_f32_16x16x32_f16(A1, B1R, cR1, 0,0,0);
    f32x4 aI = __builtin_amdgcn_mfma_f32_16x16x32_f16(A1, B1I, cI1, 0,0,0);
    #pragma unroll
    for (int r=0;r<4;++r)
      ob[(kb*4+r)*17 + o] = f2h2(fmaxf(aR[r],0.f), fmaxf(aI[r],0.f));
    f16x8 A2;
    { int4 tmp;
      const int ab = wid*(16*17) + o*17 + kb*4;
      tmp.x=o1bI[ab]; tmp.y=o1bI[ab+1]; tmp.z=o1bI[ab+2]; tmp.w=o1bI[ab+3];
      A2 = __builtin_bit_cast(f16x8, tmp); }
    f32x4 oR = __builtin_amdgcn_mfma_f32_16x16x32_f16(A2, B2R, cR2, 0,0,0);
    f32x4 oI = __builtin_amdgcn_mfma_f32_16x16x32_f16(A2, B2I, cI2, 0,0,0);
    #pragma unroll
    for (int r=0;r<4;++r)
      xp[(p0 + kb*4 + r)*17 + o] = f2h2(sshrink(oR[r]), sshrink(oI[r]));
  }
  __syncthreads();

  #pragma unroll
  for (int i=0;i<16;++i) data[(i<<8) + t] = xp[t*17 + i];
  __syncthreads();

  fft256<1,false>(data, 16, t, 256);
}

// grid (128, 8, 4): wf<128 from buf2
__global__ __launch_bounds__(256) void k_spec(__half2* __restrict__ buf2,
    const float* __restrict__ w1, const float* __restrict__ b1,
    const float* __restrict__ w2, const float* __restrict__ b2)
{
  __shared__ __half2 data[16*256];
  __shared__ __half2 xp[256*17];
  __shared__ __half2 o1b[4*16*17];
  const int t = threadIdx.x;
  const int wf = blockIdx.x, n = blockIdx.y, b = blockIdx.z;
  __half2* chunk = buf2 + ((size_t)((b*8 + n)*128 + wf) << 12);
  #pragma unroll
  for (int p=0; p<4; ++p) ((float4*)data)[(p<<8)+t] = ((const float4*)chunk)[(p<<8)+t];
  __syncthreads();
  spec_body(data, xp, o1b, n, w1,b1,w2,b2, t);
  #pragma unroll
  for (int p=0; p<4; ++p) ((float4*)chunk)[(p<<8)+t] = ((const float4*)data)[(p<<8)+t];
}

// grid (8, 4): wf==128 (Nyquist) gathered straight from buf1 col 128
__global__ __launch_bounds__(256) void k_spec_nyq(__half2* __restrict__ buf1,
    const float* __restrict__ w1, const float* __restrict__ b1,
    const float* __restrict__ w2, const float* __restrict__ b2)
{
  __shared__ __half2 data[16*256];
  __shared__ __half2 xp[256*17];
  __shared__ __half2 o1b[4*16*17];
  const int t = threadIdx.x;
  const int n = blockIdx.x, b = blockIdx.y;
  #pragma unroll
  for (int i=0;i<16;++i)
    data[(i<<8) + t] = buf1[((size_t)(b*128 + n*16 + i)*256 + t)*WFP + 128];
  __syncthreads();
  spec_body(data, xp, o1b, n, w1,b1,w2,b2, t);
  #pragma unroll
  for (int i=0;i<16;++i)
    buf1[((size_t)(b*128 + n*16 + i)*256 + t)*WFP + 128] = data[(i<<8) + t];
}

// ---------------- T2: [B][n][wf][i][H] -> [B][C][H][132] cols 0..127 ----------------
__global__ __launch_bounds__(256) void k_t2(const __half2* __restrict__ src, __half2* __restrict__ dst)
{
  __shared__ __half2 tile[32][33];
  const int t = threadIdx.x;
  const int wt = blockIdx.x;
  const int ht = blockIdx.y & 7, c = blockIdx.y >> 3, b = blockIdx.z;
  const int h0 = ht<<5, wf0 = wt<<5;
  const int tr = t>>5, tc = t&31;
  const int n = c>>4, ii = c&15;
  const size_t sbase = (size_t)(b*8 + n)*128;
  #pragma unroll
  for (int p=0; p<4; ++p){
    const int wf = wf0 + (p<<3) + tr, hh = h0 + tc;
    tile[(p<<3)+tr][tc] = src[((sbase + wf)*16 + ii)*256 + hh];
  }
  __syncthreads();
  const size_t dbase = (size_t)(b*128 + c)*256;
  #pragma unroll
  for (int p=0; p<4; ++p){
    const int hh = h0 + (p<<3) + tr, wf = wf0 + tc;
    dst[(dbase + hh)*WFP + wf] = tile[tc][(p<<3)+tr];
  }
}

// ---------------- IFFTW: irfft along W + s = h + y/256 -> st f16 ----------------
// grid 2048 = (bh<<1)|half; 32 packed rows per block; 32KB LDS; swizzled
__global__ __launch_bounds__(256) void k_ifftw(const __half2* __restrict__ buf1,
    const f16* __restrict__ h2t, f16* __restrict__ st)
{
  __shared__ __half2 fb[32*256];
  const int t = threadIdx.x;
  const int bh = blockIdx.x >> 1, half = blockIdx.x & 1;
  const int b = bh >> 8, h = bh & 255;

  const int k = t;
  const int km = (256 - t) & 255;
  const bool lo = (k <= 128);
  const int kk = lo ? k : km;
  #pragma unroll
  for (int it=0; it<32; ++it){
    const int ch = half*64 + 2*it;
    const size_t pa = ((size_t)(b*128 + ch)*256 + h)*WFP;
    const float2 va = h2f2(buf1[pa + kk]);
    const float2 vb = h2f2(buf1[pa + 256*WFP + kk]);
    float2 Z = lo ? make_float2(va.x - vb.y, va.y + vb.x)
                  : make_float2(va.x + vb.y, vb.x - va.y);
    if (k == 0 || k == 128) Z = make_float2(va.x, vb.x);
    fb[swz((it<<8) + rev4(k))] = f2h2(Z.x, Z.y);
  }
  __syncthreads();

  fft256<1,true>(fb, 32, t, 256);   // y (unnormalized: 256x ortho)

  const size_t pg = (size_t)bh*256 + t;
  const f16* hrow = h2t + pg*128 + half*64;
  f16* srow = st + pg*128 + half*64;
  #pragma unroll
  for (int i=0;i<8;++i){
    const f16x8 hv = ((const f16x8*)hrow)[i];
    f16x8 sv;
    #pragma unroll
    for (int j=0;j<4;++j){
      const float2 y = h2f2(fb[swz((i*4+j)*256 + t)]);
      sv[2*j]   = (f16)((float)hv[2*j]   + y.x*0.00390625f);
      sv[2*j+1] = (f16)((float)hv[2*j+1] + y.y*0.00390625f);
    }
    ((f16x8*)srow)[i] = sv;
  }
}

// ---------------- GEMM2: out = p2 . s + p2b + x, MFMA ----------------
// grid 2048: tile M=128 o x N=128 pixels
__global__ __launch_bounds__(256) void k_gemm2(const f16* __restrict__ st, const float* __restrict__ w,
    const float* __restrict__ bias, const float* __restrict__ xg, float* __restrict__ outg)
{
  __shared__ f16 sa[128][72];
  __shared__ f16 wl[128][72];
  typedef _Float16 f16x2 __attribute__((ext_vector_type(2)));
  const int t = threadIdx.x, l = t&63, wid = t>>6;
  const int col = l&31;
  const size_t pg0 = (size_t)blockIdx.x * 128;
  f32x16 acc0=zero16(), acc1=zero16(), acc2=zero16(), acc3=zero16();
  for (int kk=0; kk<2; ++kk){
    __syncthreads();
    { const int row=t>>1, cb=(t&1)*32;
      const f16x8* src=(const f16x8*)(st + (pg0+row)*128 + kk*64 + cb);
      f16x8* dst=(f16x8*)&sa[row][cb];
      dst[0]=src[0]; dst[1]=src[1]; dst[2]=src[2]; dst[3]=src[3]; }
    { const int row=t>>1, cb=(t&1)*32;
      const float4* src=(const float4*)(w + row*128 + kk*64 + cb);
      #pragma unroll
      for(int i=0;i<8;++i){ const float4 v=src[i];
        f16x2 p0={(f16)v.x,(f16)v.y}, p1={(f16)v.z,(f16)v.w};
        *(f16x2*)&wl[row][cb+4*i]=p0; *(f16x2*)&wl[row][cb+4*i+2]=p1; } }
    __syncthreads();
    #pragma unroll
    for (int c=0;c<4;++c){
      const int ko = c*16 + (l>>5)*8;
      const f16x8 a  = *(const f16x8*)&wl[wid*32+col][ko];
      const f16x8 v0 = *(const f16x8*)&sa[  0+col][ko];
      const f16x8 v1 = *(const f16x8*)&sa[ 32+col][ko];
      const f16x8 v2 = *(const f16x8*)&sa[ 64+col][ko];
      const f16x8 v3 = *(const f16x8*)&sa[ 96+col][ko];
      acc0 = __builtin_amdgcn_mfma_f32_32x32x16_f16(a, v0, acc0, 0,0,0);
      acc1 = __builtin_amdgcn_mfma_f32_32x32x16_f16(a, v1, acc1, 0,0,0);
      acc2 = __builtin_amdgcn_mfma_f32_32x32x16_f16(a, v2, acc2, 0,0,0);
      acc3 = __builtin_amdgcn_mfma_f32_32x32x16_f16(a, v3, acc3, 0,0,0);
    }
  }
  const int b = (int)(pg0>>16), hw0 = (int)(pg0 & 65535);
  const int orow = wid*32 + 4*(l>>5);
  auto store2 = [&](const f32x16& A, int nt){
    #pragma unroll
    for (int r=0;r<16;++r){
      const int o = orow + (r&3) + 8*(r>>2);
      const size_t addr = (((size_t)(b*128+o))<<16) + (size_t)(hw0 + nt*32 + col);
      outg[addr] = A[r] + bias[o] + xg[addr];
    }
  };
  store2(acc0,0); store2(acc1,1); store2(acc2,2); store2(acc3,3);
}

extern "C" void kernel_launch(void* const* d_in, const int* in_sizes, int n_in,
                              void* d_out, int out_size, void* d_ws, size_t ws_size,
                              hipStream_t stream)
{
  (void)in_sizes; (void)n_in; (void)out_size;
  const float* x   = (const float*)d_in[0];
  const float* p1w = (const float*)d_in[1];
  const float* p1b = (const float*)d_in[2];
  const float* w1  = (const float*)d_in[3];
  const float* b1  = (const float*)d_in[4];
  const float* w2  = (const float*)d_in[5];
  const float* b2  = (const float*)d_in[6];
  const float* p2w = (const float*)d_in[7];
  const float* p2b = (const float*)d_in[8];
  float* out = (float*)d_out;

  const size_t BUF1_B = 4UL*128*256*WFP*4;   // 69,206,016  (ws, proven to fit)
  const size_t ST_B   = 262144UL*128*2;      // 67,108,864
  __half2* buf1 = (__half2*)d_ws;
  __half2* buf2 = (__half2*)d_out;
  f16*     h2t  = (f16*)((char*)d_out + ST_B);
  const bool bigws = ws_size >= BUF1_B + ST_B;
  f16* st_w = bigws ? (f16*)((char*)d_ws + BUF1_B) : (f16*)d_out;
  f16* st_r = bigws ? st_w : (f16*)d_ws;

  k_gemm1   <<<dim3(2048),      dim3(256), 0, stream>>>(x, p1w, p1b, h2t);
  k_fftw    <<<dim3(2048),      dim3(256), 0, stream>>>(h2t, buf1);
  k_t1      <<<dim3(4,1024,4),  dim3(256), 0, stream>>>(buf1, buf2);
  k_spec    <<<dim3(128,8,4),   dim3(256), 0, stream>>>(buf2, w1, b1, w2, b2);
  k_spec_nyq<<<dim3(8,4),       dim3(256), 0, stream>>>(buf1, w1, b1, w2, b2);
  k_t2      <<<dim3(4,1024,4),  dim3(256), 0, stream>>>(buf2, buf1);
  k_ifftw   <<<dim3(2048),      dim3(256), 0, stream>>>(buf1, h2t, st_w);
  if (!bigws) (void)hipMemcpyAsync(d_ws, d_out, ST_B, hipMemcpyDeviceToDevice, stream);
  k_gemm2   <<<dim3(2048),      dim3(256), 0, stream>>>(st_r, p2w, p2b, x, out);
}

// Round 8
// 373.646 us; speedup vs baseline: 4.0216x; 1.0312x over previous
//
#include <hip/hip_runtime.h>
#include <hip/hip_fp16.h>

#define DEVI __device__ __forceinline__

// B=4, C=128, H=W=256, Wf=129 (buf1 stride 132), nb=8, bs=16
#define WFP 132

typedef _Float16 f16;
typedef _Float16 f16x8 __attribute__((ext_vector_type(8)));
typedef _Float16 f16x4 __attribute__((ext_vector_type(4)));
typedef float    f32x4  __attribute__((ext_vector_type(4)));
typedef float    f32x16 __attribute__((ext_vector_type(16)));

DEVI float2 cmul(float2 a, float2 b){ return make_float2(fmaf(a.x,b.x,-(a.y*b.y)), fmaf(a.x,b.y,a.y*b.x)); }
DEVI float2 h2f2(__half2 v){ return make_float2(__low2float(v), __high2float(v)); }
DEVI __half2 f2h2(float a, float b){ return __floats2half2_rn(a, b); }
DEVI int rev4(int k){ return ((k&3)<<6) | (((k>>2)&3)<<4) | (((k>>4)&3)<<2) | ((k>>6)&3); }
// tanh-form GELU (max err ~3e-3; erff is 3x the VALU cost). inf-safe via __expf.
DEVI float gelu(float v){
  const float u2 = 1.5957691216057308f*v*(1.0f + 0.044715f*v*v);   // 2*sqrt(2/pi)*...
  const float e = __expf(u2);
  return v - v/(e + 1.0f);   // 0.5v(1+tanh(u)) = v*e/(e+1) = v - v/(e+1)
}
DEVI float sshrink(float v){ return v > 0.01f ? v-0.01f : (v < -0.01f ? v+0.01f : 0.0f); }
// LDS bank swizzle (word-granular involution): folds addr[7:5] into addr[2:0].
DEVI int swz(int a){ return a ^ ((a>>5)&7); }
DEVI f32x16 zero16(){
  f32x16 z;
#pragma unroll
  for (int i=0;i<16;++i) z[i]=0.f;
  return z;
}

// In-place FFT over `rows` rows of 256 complex values (half2 in LDS, fp32 math).
// DIR=-1: forward DIF (natural in -> base-4 digit-reversed out).
// DIR=+1: inverse DIT (digit-reversed in -> natural out, UNNORMALIZED).
// SW: apply bank swizzle to all LDS addresses (caller must use the same swizzle).
template<int DIR, bool SW>
DEVI void fft256(__half2* d, int rows, int tid, int nthr){
  const int nbf = rows<<6;
  #pragma unroll
  for (int si=0; si<4; ++si){
    const int lq = (DIR<0) ? (6-2*si) : (2*si);
    const int q4 = 1<<lq;
    const int tws = 64>>lq;
    for (int u = tid; u < nbf; u += nthr){
      const int row = u>>6, w = u&63;
      const int j = w & (q4-1);
      const int blk = w >> lq;
      const int base = (row<<8) + (blk<<(lq+2)) + j;
      const int a0 = SW ? swz(base)        : base;
      const int a1 = SW ? swz(base+q4)     : base+q4;
      const int a2 = SW ? swz(base+2*q4)   : base+2*q4;
      const int a3 = SW ? swz(base+3*q4)   : base+3*q4;
      const int e = j*tws;
      float sn, cs;
      __sincosf((float)(DIR*e) * 0.0245436926061703f, &sn, &cs);
      const float2 w1 = make_float2(cs, sn);
      const float2 w2 = make_float2(cs*cs - sn*sn, 2.f*cs*sn);
      const float2 w3 = cmul(w2, w1);
      if (DIR < 0){
        float2 x0 = h2f2(d[a0]);
        float2 x1 = h2f2(d[a1]);
        float2 x2 = h2f2(d[a2]);
        float2 x3 = h2f2(d[a3]);
        float2 t0 = make_float2(x0.x+x2.x, x0.y+x2.y);
        float2 t1 = make_float2(x0.x-x2.x, x0.y-x2.y);
        float2 t2 = make_float2(x1.x+x3.x, x1.y+x3.y);
        float2 t3 = make_float2(x1.y-x3.y, x3.x-x1.x);
        float2 u1 = cmul(make_float2(t1.x+t3.x, t1.y+t3.y), w1);
        float2 u2 = cmul(make_float2(t0.x-t2.x, t0.y-t2.y), w2);
        float2 u3 = cmul(make_float2(t1.x-t3.x, t1.y-t3.y), w3);
        d[a0] = f2h2(t0.x+t2.x, t0.y+t2.y);
        d[a1] = f2h2(u1.x, u1.y);
        d[a2] = f2h2(u2.x, u2.y);
        d[a3] = f2h2(u3.x, u3.y);
      } else {
        float2 x0  = h2f2(d[a0]);
        float2 b1v = cmul(h2f2(d[a1]), w1);
        float2 b2v = cmul(h2f2(d[a2]), w2);
        float2 b3v = cmul(h2f2(d[a3]), w3);
        float2 t0 = make_float2(x0.x+b2v.x, x0.y+b2v.y);
        float2 t1 = make_float2(x0.x-b2v.x, x0.y-b2v.y);
        float2 t2 = make_float2(b1v.x+b3v.x, b1v.y+b3v.y);
        float2 t3 = make_float2(-(b1v.y-b3v.y), b1v.x-b3v.x);
        d[a0] = f2h2(t0.x+t2.x, t0.y+t2.y);
        d[a1] = f2h2(t1.x+t3.x, t1.y+t3.y);
        d[a2] = f2h2(t0.x-t2.x, t0.y-t2.y);
        d[a3] = f2h2(t1.x-t3.x, t1.y-t3.y);
      }
    }
    __syncthreads();
  }
}

// ---------------- GEMM1 (reg-staged prefetch): h^T[pg][co] = gelu(p1w.x + p1b) ----------------
// grid 2048: tile M=128 pixels x N=128 co, K=128 in 4 steps of 32. 4 waves.
// xa32: [c][px] f32; staged via regs (issue loads for step cs+1 under step cs's compute).
__global__ __launch_bounds__(256) void k_gemm1(const float* __restrict__ xg, const float* __restrict__ w,
    const float* __restrict__ bias, f16* __restrict__ h2t)
{
  __shared__ f16 wl[128][132];     // 33792 B
  __shared__ float xa32[32][128];  // 16384 B  -> total 50176 B: 3 blocks/CU
  const int t = threadIdx.x, l = t&63, wid = t>>6;
  const size_t pg0 = (size_t)blockIdx.x * 128;
  const int b = (int)(pg0>>16), hw0 = (int)(pg0&65535);

  // ---- stage w (16384 f32) once: flat-coalesced float4, f16x4 b64 writes ----
  #pragma unroll
  for (int i=0;i<16;++i){
    const int f4 = i*256 + t;
    const int row = f4>>5, col = (f4&31)*4;
    const float4 v = ((const float4*)w)[f4];
    const f16x4 pk = {(f16)v.x,(f16)v.y,(f16)v.z,(f16)v.w};
    *(f16x4*)&wl[row][col] = pk;
  }

  f32x16 acc[4];
  #pragma unroll
  for (int nt=0;nt<4;++nt) acc[nt]=zero16();

  // x staging map: 1024 float4 per step; thread handles idx = i*256+t (i<4):
  // row = idx>>5 (c-local 0..31), c4 = idx&31 -> 16B at xa32[row][c4*4]; global coalesced.
  float4 xr0, xr1, xr2, xr3;
  auto issue = [&](int cs){
    const float* bp = xg + (((size_t)(b*128 + cs*32))<<16) + hw0;
    xr0 = *(const float4*)(bp + (((size_t)((0*256+t)>>5))<<16) + ((0*256+t)&31)*4);
    xr1 = *(const float4*)(bp + (((size_t)((1*256+t)>>5))<<16) + ((1*256+t)&31)*4);
    xr2 = *(const float4*)(bp + (((size_t)((2*256+t)>>5))<<16) + ((2*256+t)&31)*4);
    xr3 = *(const float4*)(bp + (((size_t)((3*256+t)>>5))<<16) + ((3*256+t)&31)*4);
  };
  auto commit = [&](){
    *(float4*)&xa32[(0*256+t)>>5][((0*256+t)&31)*4] = xr0;
    *(float4*)&xa32[(1*256+t)>>5][((1*256+t)&31)*4] = xr1;
    *(float4*)&xa32[(2*256+t)>>5][((2*256+t)&31)*4] = xr2;
    *(float4*)&xa32[(3*256+t)>>5][((3*256+t)&31)*4] = xr3;
  };

  issue(0);
  const int px = wid*32 + (l&31);
  for (int cs=0; cs<4; ++cs){
    __syncthreads();   // xa32 free (prev step's ds_reads done); wl staged (cs=0)
    commit();
    __syncthreads();   // xa32 visible to all waves
    if (cs < 3) issue(cs+1);   // prefetch: HBM latency hides under compute below
    #pragma unroll
    for (int kq=0; kq<2; ++kq){
      const int k0 = kq*16 + (l>>5)*8;
      f16x8 A;
      #pragma unroll
      for (int j=0;j<8;++j) A[j] = (f16)xa32[k0 + j][px];
      #pragma unroll
      for (int nt=0; nt<4; ++nt){
        const f16x8 Bf = *(const f16x8*)&wl[nt*32 + (l&31)][cs*32 + k0];
        acc[nt] = __builtin_amdgcn_mfma_f32_32x32x16_f16(A, Bf, acc[nt], 0,0,0);
      }
    }
  }
  #pragma unroll
  for (int nt=0;nt<4;++nt){
    const int co = nt*32 + (l&31);
    const float bi = bias[co];
    #pragma unroll
    for (int r=0;r<16;++r){
      const int p = wid*32 + (r&3) + 8*(r>>2) + 4*(l>>5);
      h2t[(pg0+(size_t)p)*128 + co] = (f16)gelu(acc[nt][r] + bi);
    }
  }
}

// ---------------- FFTW: rfft along W of h rows -> buf1 ----------------
// grid 2048 = (bh<<1)|half; 32 packed rows (64 channels) per block; 32KB LDS; swizzled
__global__ __launch_bounds__(256) void k_fftw(const f16* __restrict__ h2t, __half2* __restrict__ buf1)
{
  __shared__ __half2 fb[32*256];
  const int t = threadIdx.x;
  const int bh = blockIdx.x >> 1, half = blockIdx.x & 1;
  const int b = bh >> 8, h = bh & 255;
  const size_t pg = (size_t)bh*256 + t;
  const f16* row = h2t + pg*128 + half*64;
  #pragma unroll
  for (int i=0;i<8;++i){
    const f16x8 v = ((const f16x8*)row)[i];
    const __half2* vp = (const __half2*)&v;
    #pragma unroll
    for (int j=0;j<4;++j) fb[swz((i*4+j)*256 + t)] = vp[j];
  }
  __syncthreads();

  fft256<-1,true>(fb, 32, t, 256);

  #pragma unroll
  for (int it=0; it<16; ++it){
    const int idx = (it<<8) + t;
    const int r = idx>>7, k = idx&127;        // r 0..31
    const float2 zk = h2f2(fb[swz((r<<8) + rev4(k))]);
    const float2 zm = h2f2(fb[swz((r<<8) + rev4((256-k)&255))]);
    const float ar = (zk.x+zm.x)*0.03125f, ai = (zk.y-zm.y)*0.03125f;
    const float br = (zk.y+zm.y)*0.03125f, bi = (zm.x-zk.x)*0.03125f;
    const int ch = half*64 + 2*r;
    const size_t pa = ((size_t)(b*128 + ch)*256 + h)*WFP + k;
    buf1[pa]           = f2h2(ar, ai);
    buf1[pa + 256*WFP] = f2h2(br, bi);
  }
  if (t < 32){   // Nyquist k=128
    const int r = t;
    const float2 zk = h2f2(fb[swz((r<<8) + rev4(128))]);
    const int ch = half*64 + 2*r;
    const size_t pa = ((size_t)(b*128 + ch)*256 + h)*WFP + 128;
    buf1[pa]           = f2h2(zk.x*0.0625f, 0.f);
    buf1[pa + 256*WFP] = f2h2(zk.y*0.0625f, 0.f);
  }
}

// ---------------- T1: [B][C][H][132] cols 0..127 -> [B][n][wf][i][H] ----------------
// grid (4, 1024, 4)
__global__ __launch_bounds__(256) void k_t1(const __half2* __restrict__ src, __half2* __restrict__ dst)
{
  __shared__ __half2 tile[32][33];
  const int t = threadIdx.x;
  const int wt = blockIdx.x;
  const int ht = blockIdx.y & 7, c = blockIdx.y >> 3, b = blockIdx.z;
  const int h0 = ht<<5, wf0 = wt<<5;
  const int tr = t>>5, tc = t&31;
  const size_t sbase = (size_t)(b*128 + c)*256;
  #pragma unroll
  for (int p=0; p<4; ++p){
    const int hh = h0 + (p<<3) + tr, wf = wf0 + tc;
    tile[(p<<3)+tr][tc] = src[(sbase + hh)*WFP + wf];
  }
  __syncthreads();
  const int n = c>>4, ii = c&15;
  const size_t dbase = (size_t)(b*8 + n)*128;
  #pragma unroll
  for (int p=0; p<4; ++p){
    const int wf = wf0 + (p<<3) + tr, hh = h0 + tc;
    dst[((dbase + wf)*16 + ii)*256 + hh] = tile[tc][(p<<3)+tr];
  }
}

// ---------------- spec body v2: FFT along H + complex block-MLP (MFMA) + inverse ----------------
DEVI void spec_body(__half2* data, __half2* xp, __half2* o1b, int n,
                    const float* __restrict__ w1, const float* __restrict__ b1,
                    const float* __restrict__ w2, const float* __restrict__ b2, int t)
{
  fft256<-1,false>(data, 16, t, 256);

  const int l = t&63, wid = t>>6;
  const int o = l&15, kb = l>>4;

  f16x8 B1R, B1I, B2R, B2I;
  #pragma unroll
  for (int j=0;j<8;++j){
    const int i = kb*4 + (j>>1);
    const float a1r = w1[(n*16+i)*16+o], a1i = w1[2048 + (n*16+i)*16+o];
    const float a2r = w2[(n*16+i)*16+o], a2i = w2[2048 + (n*16+i)*16+o];
    B1R[j] = (f16)(((j&1) ? -a1i : a1r) * 0.0625f);
    B1I[j] = (f16)(((j&1) ?  a1r : a1i) * 0.0625f);
    B2R[j] = (f16)((j&1) ? -a2i : a2r);
    B2I[j] = (f16)((j&1) ?  a2r : a2i);
  }
  const float b1r = b1[n*16+o],     b1i = b1[128 + n*16+o];
  const float b2r = b2[n*16+o],     b2i = b2[128 + n*16+o];
  const f32x4 cR1 = {b1r,b1r,b1r,b1r}, cI1 = {b1i,b1i,b1i,b1i};
  const f32x4 cR2 = {b2r,b2r,b2r,b2r}, cI2 = {b2i,b2i,b2i,b2i};

  #pragma unroll
  for (int i=0;i<16;++i) xp[t*17 + i] = data[(i<<8) + t];
  __syncthreads();

  const int* xpI  = (const int*)xp;
  const int* o1bI = (const int*)o1b;
  __half2*  ob    = o1b + wid*(16*17);

  #pragma unroll
  for (int tt=0; tt<4; ++tt){
    const int p0 = wid*64 + tt*16;
    f16x8 A1;
    { int4 tmp;
      const int ab = (p0 + o)*17 + kb*4;
      tmp.x=xpI[ab]; tmp.y=xpI[ab+1]; tmp.z=xpI[ab+2]; tmp.w=xpI[ab+3];
      A1 = __builtin_bit_cast(f16x8, tmp); }
    f32x4 aR = __builtin_amdgcn_mfma_f32_16x16x32_f16(A1, B1R, cR1, 0,0,0);
    f32x4 aI = __builtin_amdgcn_mfma_f32_16x16x32_f16(A1, B1I, cI1, 0,0,0);
    #pragma unroll
    for (int r=0;r<4;++r)
      ob[(kb*4+r)*17 + o] = f2h2(fmaxf(aR[r],0.f), fmaxf(aI[r],0.f));
    f16x8 A2;
    { int4 tmp;
      const int ab = wid*(16*17) + o*17 + kb*4;
      tmp.x=o1bI[ab]; tmp.y=o1bI[ab+1]; tmp.z=o1bI[ab+2]; tmp.w=o1bI[ab+3];
      A2 = __builtin_bit_cast(f16x8, tmp); }
    f32x4 oR = __builtin_amdgcn_mfma_f32_16x16x32_f16(A2, B2R, cR2, 0,0,0);
    f32x4 oI = __builtin_amdgcn_mfma_f32_16x16x32_f16(A2, B2I, cI2, 0,0,0);
    #pragma unroll
    for (int r=0;r<4;++r)
      xp[(p0 + kb*4 + r)*17 + o] = f2h2(sshrink(oR[r]), sshrink(oI[r]));
  }
  __syncthreads();

  #pragma unroll
  for (int i=0;i<16;++i) data[(i<<8) + t] = xp[t*17 + i];
  __syncthreads();

  fft256<1,false>(data, 16, t, 256);
}

// grid (128, 8, 4): wf<128 from buf2
__global__ __launch_bounds__(256) void k_spec(__half2* __restrict__ buf2,
    const float* __restrict__ w1, const float* __restrict__ b1,
    const float* __restrict__ w2, const float* __restrict__ b2)
{
  __shared__ __half2 data[16*256];
  __shared__ __half2 xp[256*17];
  __shared__ __half2 o1b[4*16*17];
  const int t = threadIdx.x;
  const int wf = blockIdx.x, n = blockIdx.y, b = blockIdx.z;
  __half2* chunk = buf2 + ((size_t)((b*8 + n)*128 + wf) << 12);
  #pragma unroll
  for (int p=0; p<4; ++p) ((float4*)data)[(p<<8)+t] = ((const float4*)chunk)[(p<<8)+t];
  __syncthreads();
  spec_body(data, xp, o1b, n, w1,b1,w2,b2, t);
  #pragma unroll
  for (int p=0; p<4; ++p) ((float4*)chunk)[(p<<8)+t] = ((const float4*)data)[(p<<8)+t];
}

// grid (8, 4): wf==128 (Nyquist) gathered straight from buf1 col 128
__global__ __launch_bounds__(256) void k_spec_nyq(__half2* __restrict__ buf1,
    const float* __restrict__ w1, const float* __restrict__ b1,
    const float* __restrict__ w2, const float* __restrict__ b2)
{
  __shared__ __half2 data[16*256];
  __shared__ __half2 xp[256*17];
  __shared__ __half2 o1b[4*16*17];
  const int t = threadIdx.x;
  const int n = blockIdx.x, b = blockIdx.y;
  #pragma unroll
  for (int i=0;i<16;++i)
    data[(i<<8) + t] = buf1[((size_t)(b*128 + n*16 + i)*256 + t)*WFP + 128];
  __syncthreads();
  spec_body(data, xp, o1b, n, w1,b1,w2,b2, t);
  #pragma unroll
  for (int i=0;i<16;++i)
    buf1[((size_t)(b*128 + n*16 + i)*256 + t)*WFP + 128] = data[(i<<8) + t];
}

// ---------------- T2: [B][n][wf][i][H] -> [B][C][H][132] cols 0..127 ----------------
__global__ __launch_bounds__(256) void k_t2(const __half2* __restrict__ src, __half2* __restrict__ dst)
{
  __shared__ __half2 tile[32][33];
  const int t = threadIdx.x;
  const int wt = blockIdx.x;
  const int ht = blockIdx.y & 7, c = blockIdx.y >> 3, b = blockIdx.z;
  const int h0 = ht<<5, wf0 = wt<<5;
  const int tr = t>>5, tc = t&31;
  const int n = c>>4, ii = c&15;
  const size_t sbase = (size_t)(b*8 + n)*128;
  #pragma unroll
  for (int p=0; p<4; ++p){
    const int wf = wf0 + (p<<3) + tr, hh = h0 + tc;
    tile[(p<<3)+tr][tc] = src[((sbase + wf)*16 + ii)*256 + hh];
  }
  __syncthreads();
  const size_t dbase = (size_t)(b*128 + c)*256;
  #pragma unroll
  for (int p=0; p<4; ++p){
    const int hh = h0 + (p<<3) + tr, wf = wf0 + tc;
    dst[(dbase + hh)*WFP + wf] = tile[tc][(p<<3)+tr];
  }
}

// ---------------- IFFTW: irfft along W + s = h + y/256 -> st f16 ----------------
// grid 2048 = (bh<<1)|half; 32 packed rows per block; 32KB LDS; swizzled
__global__ __launch_bounds__(256) void k_ifftw(const __half2* __restrict__ buf1,
    const f16* __restrict__ h2t, f16* __restrict__ st)
{
  __shared__ __half2 fb[32*256];
  const int t = threadIdx.x;
  const int bh = blockIdx.x >> 1, half = blockIdx.x & 1;
  const int b = bh >> 8, h = bh & 255;

  const int k = t;
  const int km = (256 - t) & 255;
  const bool lo = (k <= 128);
  const int kk = lo ? k : km;
  #pragma unroll
  for (int it=0; it<32; ++it){
    const int ch = half*64 + 2*it;
    const size_t pa = ((size_t)(b*128 + ch)*256 + h)*WFP;
    const float2 va = h2f2(buf1[pa + kk]);
    const float2 vb = h2f2(buf1[pa + 256*WFP + kk]);
    float2 Z = lo ? make_float2(va.x - vb.y, va.y + vb.x)
                  : make_float2(va.x + vb.y, vb.x - va.y);
    if (k == 0 || k == 128) Z = make_float2(va.x, vb.x);
    fb[swz((it<<8) + rev4(k))] = f2h2(Z.x, Z.y);
  }
  __syncthreads();

  fft256<1,true>(fb, 32, t, 256);   // y (unnormalized: 256x ortho)

  const size_t pg = (size_t)bh*256 + t;
  const f16* hrow = h2t + pg*128 + half*64;
  f16* srow = st + pg*128 + half*64;
  #pragma unroll
  for (int i=0;i<8;++i){
    const f16x8 hv = ((const f16x8*)hrow)[i];
    f16x8 sv;
    #pragma unroll
    for (int j=0;j<4;++j){
      const float2 y = h2f2(fb[swz((i*4+j)*256 + t)]);
      sv[2*j]   = (f16)((float)hv[2*j]   + y.x*0.00390625f);
      sv[2*j+1] = (f16)((float)hv[2*j+1] + y.y*0.00390625f);
    }
    ((f16x8*)srow)[i] = sv;
  }
}

// ---------------- GEMM2: out = p2 . s + p2b + x, MFMA ----------------
// grid 2048: tile M=128 o x N=128 pixels
__global__ __launch_bounds__(256) void k_gemm2(const f16* __restrict__ st, const float* __restrict__ w,
    const float* __restrict__ bias, const float* __restrict__ xg, float* __restrict__ outg)
{
  __shared__ f16 sa[128][72];
  __shared__ f16 wl[128][72];
  typedef _Float16 f16x2 __attribute__((ext_vector_type(2)));
  const int t = threadIdx.x, l = t&63, wid = t>>6;
  const int col = l&31;
  const size_t pg0 = (size_t)blockIdx.x * 128;
  f32x16 acc0=zero16(), acc1=zero16(), acc2=zero16(), acc3=zero16();
  for (int kk=0; kk<2; ++kk){
    __syncthreads();
    { const int row=t>>1, cb=(t&1)*32;
      const f16x8* src=(const f16x8*)(st + (pg0+row)*128 + kk*64 + cb);
      f16x8* dst=(f16x8*)&sa[row][cb];
      dst[0]=src[0]; dst[1]=src[1]; dst[2]=src[2]; dst[3]=src[3]; }
    { const int row=t>>1, cb=(t&1)*32;
      const float4* src=(const float4*)(w + row*128 + kk*64 + cb);
      #pragma unroll
      for(int i=0;i<8;++i){ const float4 v=src[i];
        f16x2 p0={(f16)v.x,(f16)v.y}, p1={(f16)v.z,(f16)v.w};
        *(f16x2*)&wl[row][cb+4*i]=p0; *(f16x2*)&wl[row][cb+4*i+2]=p1; } }
    __syncthreads();
    #pragma unroll
    for (int c=0;c<4;++c){
      const int ko = c*16 + (l>>5)*8;
      const f16x8 a  = *(const f16x8*)&wl[wid*32+col][ko];
      const f16x8 v0 = *(const f16x8*)&sa[  0+col][ko];
      const f16x8 v1 = *(const f16x8*)&sa[ 32+col][ko];
      const f16x8 v2 = *(const f16x8*)&sa[ 64+col][ko];
      const f16x8 v3 = *(const f16x8*)&sa[ 96+col][ko];
      acc0 = __builtin_amdgcn_mfma_f32_32x32x16_f16(a, v0, acc0, 0,0,0);
      acc1 = __builtin_amdgcn_mfma_f32_32x32x16_f16(a, v1, acc1, 0,0,0);
      acc2 = __builtin_amdgcn_mfma_f32_32x32x16_f16(a, v2, acc2, 0,0,0);
      acc3 = __builtin_amdgcn_mfma_f32_32x32x16_f16(a, v3, acc3, 0,0,0);
    }
  }
  const int b = (int)(pg0>>16), hw0 = (int)(pg0 & 65535);
  const int orow = wid*32 + 4*(l>>5);
  auto store2 = [&](const f32x16& A, int nt){
    #pragma unroll
    for (int r=0;r<16;++r){
      const int o = orow + (r&3) + 8*(r>>2);
      const size_t addr = (((size_t)(b*128+o))<<16) + (size_t)(hw0 + nt*32 + col);
      outg[addr] = A[r] + bias[o] + xg[addr];
    }
  };
  store2(acc0,0); store2(acc1,1); store2(acc2,2); store2(acc3,3);
}

extern "C" void kernel_launch(void* const* d_in, const int* in_sizes, int n_in,
                              void* d_out, int out_size, void* d_ws, size_t ws_size,
                              hipStream_t stream)
{
  (void)in_sizes; (void)n_in; (void)out_size;
  const float* x   = (const float*)d_in[0];
  const float* p1w = (const float*)d_in[1];
  const float* p1b = (const float*)d_in[2];
  const float* w1  = (const float*)d_in[3];
  const float* b1  = (const float*)d_in[4];
  const float* w2  = (const float*)d_in[5];
  const float* b2  = (const float*)d_in[6];
  const float* p2w = (const float*)d_in[7];
  const float* p2b = (const float*)d_in[8];
  float* out = (float*)d_out;

  const size_t BUF1_B = 4UL*128*256*WFP*4;   // 69,206,016  (ws, proven to fit)
  const size_t ST_B   = 262144UL*128*2;      // 67,108,864
  __half2* buf1 = (__half2*)d_ws;
  __half2* buf2 = (__half2*)d_out;
  f16*     h2t  = (f16*)((char*)d_out + ST_B);
  const bool bigws = ws_size >= BUF1_B + ST_B;
  f16* st_w = bigws ? (f16*)((char*)d_ws + BUF1_B) : (f16*)d_out;
  f16* st_r = bigws ? st_w : (f16*)d_ws;

  k_gemm1   <<<dim3(2048),      dim3(256), 0, stream>>>(x, p1w, p1b, h2t);
  k_fftw    <<<dim3(2048),      dim3(256), 0, stream>>>(h2t, buf1);
  k_t1      <<<dim3(4,1024,4),  dim3(256), 0, stream>>>(buf1, buf2);
  k_spec    <<<dim3(128,8,4),   dim3(256), 0, stream>>>(buf2, w1, b1, w2, b2);
  k_spec_nyq<<<dim3(8,4),       dim3(256), 0, stream>>>(buf1, w1, b1, w2, b2);
  k_t2      <<<dim3(4,1024,4),  dim3(256), 0, stream>>>(buf2, buf1);
  k_ifftw   <<<dim3(2048),      dim3(256), 0, stream>>>(buf1, h2t, st_w);
  if (!bigws) (void)hipMemcpyAsync(d_ws, d_out, ST_B, hipMemcpyDeviceToDevice, stream);
  k_gemm2   <<<dim3(2048),      dim3(256), 0, stream>>>(st_r, p2w, p2b, x, out);
}